// Round 5
// baseline (219.733 us; speedup 1.0000x reference)
//
#include <hip/hip_runtime.h>
#include <hip/hip_bf16.h>

// ---------------------------------------------------------------------------
// Qwen2VL SDPA attention block, MI355X/gfx950. fp32 in/out, bf16 MFMA inside.
// T=4096, D=1280, H=16, HD=80, 8 segments of 512 (block-diagonal attention).
// Pipeline: [C]  convert hidden/qkv_w/proj_w fp32->bf16 (one fused kernel)
//           [K1] gemm_qkv: 128x160 tile, 2-phase dbuf global_load_lds,
//                (256,4), XCD map; FUSED ROPE epilogue -> Qh/Kh [h][t][96],
//                V -> Vt[h][d][t]   (R2 form, measured 61.5 us)
//           [K3] attention: phase A reads K fragments DIRECT from L2 (no
//                LDS staging, zero barriers); V DMA double-buffered; exact
//                softmax; P via LDS
//           [K4] gemm_proj: 64x128 tile, 4-slot ring, counted vmcnt
//                (R4 form; inferred -18 us vs 2-phase)
// R1: chunk XOR-swizzle -> bank conflicts 4.4M -> 0. R2: XCD map, FETCH at
// floor. R3: counted-vmcnt + tight reg bound => spill disaster. R4: ring at
// 2 blocks/CU => K1 80 us (occupancy loss > pipeline gain) but K4 ring
// better; totals R2==R4 => K3+K4 ~130 us, K3 ~55 us = biggest target.
// R5: revert K1 to R2; keep K4 ring; K3 phase-A de-staging (L2-direct).
// ---------------------------------------------------------------------------

#define T_DIM 4096
#define D_DIM 1280
#define NH    16
#define HD    80
#define HDP   96      // head dim padded to 3x32 for K=32 MFMA steps
#define SEG   512
#define VLP   136     // P LDS row stride (pad off pow2)
#define RLS   80      // rope-epilogue LDS row stride

typedef __bf16 bf16;
typedef bf16  bf16x4 __attribute__((ext_vector_type(4)));
typedef bf16  bf16x8 __attribute__((ext_vector_type(8)));
typedef float f32x4  __attribute__((ext_vector_type(4)));

#define WAITVM(n) asm volatile("s_waitcnt vmcnt(" #n ")" ::: "memory")
#define SBAR()    asm volatile("s_barrier" ::: "memory")

__device__ __forceinline__ void gload16(const bf16* g, bf16* l) {
  __builtin_amdgcn_global_load_lds(
      (const __attribute__((address_space(1))) void*)g,
      (__attribute__((address_space(3))) void*)l, 16, 0, 0);
}

// ---------------------------------------------------------------------------
// Fused fp32->bf16 convert of hidden (1310720 f4), qkv_w (1228800 f4),
// proj_w (409600 f4). Grid covers 2949120 float4 groups.
// ---------------------------------------------------------------------------
__global__ __launch_bounds__(256) void cvt_all(
    const float* __restrict__ hid, const float* __restrict__ qw,
    const float* __restrict__ pw, bf16* __restrict__ hb,
    bf16* __restrict__ qwb, bf16* __restrict__ pwb)
{
  int i = blockIdx.x * 256 + threadIdx.x;
  const float* src; bf16* dst; int off;
  if (i < 1310720)      { src = hid; dst = hb;  off = i; }
  else if (i < 2539520) { src = qw;  dst = qwb; off = i - 1310720; }
  else                  { src = pw;  dst = pwb; off = i - 2539520; }
  float4 v = ((const float4*)src)[off];
  ((bf16x4*)dst)[off] = (bf16x4){(bf16)v.x, (bf16)v.y, (bf16)v.z, (bf16)v.w};
}

// ---------------------------------------------------------------------------
// K1: qkv GEMM, BM=128 BN=160 BK=32, 4 waves (2x2), wave = 64x80 (one head
// per wave-half). 2-phase dbuf via global_load_lds; __syncthreads drains.
// LDS rows 32 bf16 = 4 chunks of 16 B, chunk c of row r holds logical chunk
// c ^ ((r>>1)&3) (pre-swizzled global source, deswizzled frag read).
// Grid: mt=lin/24, nt=lin%24 (24%8==0 => XCD=nt%8, W-tile L2-resident).
// Epilogue: Q/K -> wave LDS -> rope -> [h][t][96] chunks XOR-swizzled by
// ((t>>1)&3); V -> Vt[h][d][T] bf16x4 scatter.
// ---------------------------------------------------------------------------
__global__ __launch_bounds__(256, 4) void gemm_qkv(
    const bf16* __restrict__ A, const bf16* __restrict__ W,
    const float* __restrict__ bias, const float* __restrict__ rot,
    bf16* __restrict__ Qh, bf16* __restrict__ Kh, bf16* __restrict__ Vt)
{
  constexpr int BM = 128, BN = 160, MI = 4, NJ = 5;
  constexpr int K = 1280;
  constexpr int STAGE = 2 * (BM + BN) * 32;       // 18432 elems
  constexpr int EPIB  = 4 * 64 * RLS;             // 20480 elems
  constexpr int LDSZ  = (STAGE > EPIB ? STAGE : EPIB);
  __shared__ __align__(16) bf16 smem[LDSZ];
  bf16* As = smem;
  bf16* Bs = smem + 2 * BM * 32;

  int tid  = threadIdx.x;
  int wave = tid >> 6, lane = tid & 63;
  int l15 = lane & 15, quad = lane >> 4;
  int q8s = ((quad ^ ((l15 >> 1) & 3)) * 8);      // frag-read deswizzle
  int mt = blockIdx.x / 24;
  int nt = blockIdx.x % 24;
  int m0 = mt * BM, n0 = nt * BN;
  int wm = (wave >> 1) * (BM / 2), wn = (wave & 1) * (BN / 2);

  int er  = tid >> 2;
  int ec8 = (((tid & 3) ^ ((tid >> 3) & 3)) * 8); // source pre-swizzle
  const bf16* ga = A + (size_t)(m0 + er) * K + ec8;
  const bf16* gb = W + (size_t)(n0 + er) * K + ec8;

  // staging: A 128 rows (2 chunks/thread), B 160 rows (2 + tid<128 third)
  auto issueN = [&](int k, int p) {
    bf16* la = As + p * (BM * 32) + tid * 8;
    bf16* lb = Bs + p * (BN * 32) + tid * 8;
    gload16(ga + k, la);
    gload16(ga + (size_t)64 * K + k, la + 2048);
    gload16(gb + k, lb);
    gload16(gb + (size_t)64 * K + k, lb + 2048);
    if (tid < 128) gload16(gb + (size_t)128 * K + k, lb + 4096);
  };

  f32x4 acc[MI][NJ];
#pragma unroll
  for (int i = 0; i < MI; ++i)
#pragma unroll
    for (int j = 0; j < NJ; ++j) acc[i][j] = (f32x4){0.f, 0.f, 0.f, 0.f};

  constexpr int NK = K / 32;
  issueN(0, 0);
  for (int kt = 0; kt < NK; ++kt) {
    int p = kt & 1;
    __syncthreads();                      // drains DMA(kt) + prev frag reads
    if (kt + 1 < NK) issueN((kt + 1) * 32, p ^ 1);
    bf16x8 af[MI], bfr[NJ];
#pragma unroll
    for (int i = 0; i < MI; ++i)
      af[i] = *(const bf16x8*)(As + p * (BM * 32) + (wm + i * 16 + l15) * 32 + q8s);
#pragma unroll
    for (int j = 0; j < NJ; ++j)
      bfr[j] = *(const bf16x8*)(Bs + p * (BN * 32) + (wn + j * 16 + l15) * 32 + q8s);
#pragma unroll
    for (int i = 0; i < MI; ++i)
#pragma unroll
      for (int j = 0; j < NJ; ++j)
        acc[i][j] = __builtin_amdgcn_mfma_f32_16x16x32_bf16(af[i], bfr[j], acc[i][j], 0, 0, 0);
  }

  int c0  = n0 + wn;                 // wave's first col = head base
  int sel = c0 / D_DIM;              // 0=Q, 1=K, 2=V (block-uniform)
  if (sel < 2) {
    // ---- fused rope epilogue ----
    __syncthreads();                 // all frag reads done; reuse smem
    bf16* Lw = smem + wave * (64 * RLS);
    int cc0 = c0 - sel * D_DIM;
    int h   = cc0 / HD;
#pragma unroll
    for (int j = 0; j < NJ; ++j) {
      float bv = bias[c0 + j * 16 + l15];
#pragma unroll
      for (int i = 0; i < MI; ++i)
#pragma unroll
        for (int r = 0; r < 4; ++r)
          Lw[(i * 16 + quad * 4 + r) * RLS + j * 16 + l15] = (bf16)(acc[i][j][r] + bv);
    }
    __syncthreads();
    int t = m0 + wm + lane;          // lane = local row
    bf16x4 x[20];
#pragma unroll
    for (int a = 0; a < 20; ++a)
      x[a] = *(const bf16x4*)(Lw + lane * RLS + a * 4);
    const float* fp = rot + t * 40;
    float fr[40];
#pragma unroll
    for (int a = 0; a < 10; ++a) {
      float4 f4 = *(const float4*)(fp + a * 4);
      fr[a * 4] = f4.x; fr[a * 4 + 1] = f4.y; fr[a * 4 + 2] = f4.z; fr[a * 4 + 3] = f4.w;
    }
    const float sc = (sel == 0) ? 0.11180339887498949f : 1.0f;
    bf16* dst = ((sel == 0) ? Qh : Kh) + ((size_t)h * T_DIM + t) * HDP;
    int ksw = (t >> 1) & 3;          // row chunk swizzle
#pragma unroll
    for (int g = 0; g < 5; ++g) {
      bf16x8 c1, c2;
#pragma unroll
      for (int bb = 0; bb < 8; ++bb) {
        int a = g * 2 + (bb >> 2), b = bb & 3;
        float cs, sn;
        __sincosf(fr[a * 4 + b], &sn, &cs);
        cs *= sc; sn *= sc;
        float xa = (float)x[a][b], xb = (float)x[a + 10][b];
        c1[bb] = (bf16)(xa * cs - xb * sn);
        c2[bb] = (bf16)(xb * cs + xa * sn);
      }
      *(bf16x8*)(dst + (g ^ ksw) * 8)       = c1;
      *(bf16x8*)(dst + ((g + 5) ^ ksw) * 8) = c2;
    }
    bf16x8 z = {};
    *(bf16x8*)(dst + (10 ^ ksw) * 8) = z;
    *(bf16x8*)(dst + (11 ^ ksw) * 8) = z;
  } else {
    // ---- V scatter (transposed, t-major) ----
#pragma unroll
    for (int j = 0; j < NJ; ++j) {
      int c = c0 + j * 16 + l15;
      float bv = bias[c];
      int cc = c - 2 * D_DIM;
      int h = cc / HD, d = cc - h * HD;
      bf16* vrow = Vt + ((size_t)h * HD + d) * T_DIM;
#pragma unroll
      for (int i = 0; i < MI; ++i) {
        int t0 = m0 + wm + i * 16 + quad * 4;
        bf16x4 pv = {(bf16)(acc[i][j][0] + bv), (bf16)(acc[i][j][1] + bv),
                     (bf16)(acc[i][j][2] + bv), (bf16)(acc[i][j][3] + bv)};
        *(bf16x4*)(vrow + t0) = pv;
      }
    }
  }
}

// ---------------------------------------------------------------------------
// K3: attention. Grid 1024; all 8 tiles of (seg,head) group g land on
// XCD g%8 => K/V L2-resident (K seg 98 KB, V seg 82 KB; 16 groups x 180 KB
// = 2.9 MB per XCD L2).
// Phase A: K fragments read DIRECT from L2 (zero barriers, compiler
// vmcnt-pipelines 96 loads against 96 MFMAs). V(0) DMA issued at kernel
// start, drains behind phase A + softmax. Phase B: V LDS double buffer
// (4-wave x 4-ks broadcast reuse), XOR chunk swizzle; P via LDS.
// Qh/Kh rows chunk-swizzled by ((t>>1)&3) (from K1); qf/kb deswizzle.
// ---------------------------------------------------------------------------
__global__ __launch_bounds__(256, 2) void attn_kernel(
    const bf16* __restrict__ Qh, const bf16* __restrict__ Kh,
    const bf16* __restrict__ Vt, bf16* __restrict__ out)
{
  // V double buffer 2 x 20480 B ([80][128]); P 17408 B => 58368 B
  __shared__ __align__(16) char smem[58368];
  bf16* Vb[2] = {(bf16*)smem, (bf16*)(smem + 20480)};
  bf16* Pl    = (bf16*)(smem + 40960);

  int lin  = blockIdx.x;
  int g    = lin & 127;        // (seg,head) group
  int tile = lin >> 7;         // 0..7
  int h    = g & 15;
  int seg  = g >> 4;
  int seg0 = seg * SEG;
  int t0   = seg0 + tile * 64;

  int tid  = threadIdx.x;
  int wave = tid >> 6;
  int lane = tid & 63;
  int l15 = lane & 15, quad = lane >> 4, q8 = quad * 8;
  int qs8 = ((quad ^ ((l15 >> 1) & 3)) * 8);   // Qh/Kh chunk deswizzle
  int tw = t0 + wave * 16;

  const bf16* khbase = Kh + ((size_t)h * T_DIM + seg0) * HDP;
  const bf16* vtbase = Vt + (size_t)h * HD * T_DIM + seg0;

  auto issueV = [&](int kc, bf16* buf) {
    const bf16* src = vtbase + kc * 128;
#pragma unroll
    for (int i = 0; i < 5; ++i) {
      int idx = i * 256 + tid;            // 0..1279
      int d = idx >> 4, ch = idx & 15;
      int chg = ch ^ (d & 7);             // XOR source-chunk swizzle
      gload16(src + (size_t)d * T_DIM + chg * 8, buf + idx * 8);
    }
  };

  issueV(0, Vb[0]);            // lands behind phase A + softmax

  bf16x8 qf[3];
  {
    const bf16* qbase = Qh + ((size_t)h * T_DIM + tw + l15) * HDP + qs8;
#pragma unroll
    for (int kk = 0; kk < 3; ++kk) qf[kk] = *(const bf16x8*)(qbase + kk * 32);
  }

  // ---- Phase A: S = Q K^T, K fragments straight from L2, no barriers ----
  f32x4 S[4][8];
#pragma unroll
  for (int kc = 0; kc < 4; ++kc) {
#pragma unroll
    for (int j = 0; j < 8; ++j) {
      const bf16* kb = khbase + (size_t)(kc * 128 + j * 16 + l15) * HDP + qs8;
      f32x4 acc = {0.f, 0.f, 0.f, 0.f};
#pragma unroll
      for (int kk = 0; kk < 3; ++kk)
        acc = __builtin_amdgcn_mfma_f32_16x16x32_bf16(qf[kk], *(const bf16x8*)(kb + kk * 32), acc, 0, 0, 0);
      S[kc][j] = acc;
    }
  }

  // ---- Softmax (exact; scale pre-folded into Q). V(0) in flight. ----
  float vsum[4];
#pragma unroll
  for (int r = 0; r < 4; ++r) {
    float m = -1e30f;
#pragma unroll
    for (int kc = 0; kc < 4; ++kc)
#pragma unroll
      for (int j = 0; j < 8; ++j) m = fmaxf(m, S[kc][j][r]);
    for (int off = 1; off < 16; off <<= 1) m = fmaxf(m, __shfl_xor(m, off));
    float s = 0.f;
#pragma unroll
    for (int kc = 0; kc < 4; ++kc)
#pragma unroll
      for (int j = 0; j < 8; ++j) {
        float e = __expf(S[kc][j][r] - m);
        S[kc][j][r] = e;
        s += e;
      }
    for (int off = 1; off < 16; off <<= 1) s += __shfl_xor(s, off);
    vsum[r] = s;
  }

  // ---- Phase B: O = P V, 4 chunks, V prefetched one chunk ahead ----
  f32x4 O[5];
#pragma unroll
  for (int n = 0; n < 5; ++n) O[n] = (f32x4){0.f, 0.f, 0.f, 0.f};
  bf16* Plw = Pl + wave * (16 * VLP);

  for (int kc = 0; kc < 4; ++kc) {
    bf16* vbuf = Vb[kc & 1];
    __syncthreads();                       // drains V(kc); prior reads done
    if (kc < 3) issueV(kc + 1, Vb[(kc & 1) ^ 1]);
#pragma unroll
    for (int j = 0; j < 8; ++j)
#pragma unroll
      for (int r = 0; r < 4; ++r)
        Plw[(quad * 4 + r) * VLP + j * 16 + l15] = (bf16)S[kc][j][r];
    __syncthreads();                       // P visible
    __builtin_amdgcn_s_setprio(1);
#pragma unroll
    for (int ks = 0; ks < 4; ++ks) {
      bf16x8 pa = *(const bf16x8*)(Plw + l15 * VLP + ks * 32 + q8);
#pragma unroll
      for (int n = 0; n < 5; ++n) {
        int d = n * 16 + l15;
        // global chunk (ks*4+quad) lives at LDS chunk ^(d&7)
        int chl = (ks * 4 + quad) ^ (d & 7);
        bf16x8 vb = *(const bf16x8*)(vbuf + d * 128 + chl * 8);
        O[n] = __builtin_amdgcn_mfma_f32_16x16x32_bf16(pa, vb, O[n], 0, 0, 0);
      }
    }
    __builtin_amdgcn_s_setprio(0);
  }

#pragma unroll
  for (int n = 0; n < 5; ++n)
#pragma unroll
    for (int r = 0; r < 4; ++r) {
      int row = tw + quad * 4 + r;
      int col = h * HD + n * 16 + l15;
      out[(size_t)row * D_DIM + col] = (bf16)(O[n][r] / vsum[r]);
    }
}

// ---------------------------------------------------------------------------
// K4: proj GEMM, BM=64 BN=128 BK=32, 4 waves, wave = 32x64 (MI=2, NJ=4).
// 4-slot LDS ring, counted vmcnt (issue kt+2; wait vmcnt(6) => tiles kt+1,
// kt+2 in flight, tile kt landed; ONE s_barrier/iter). 49152 B LDS =>
// 3 blocks/CU. fp32 out + bias. A-sharing XCD swizzle (lin%8 == mt%8).
// ---------------------------------------------------------------------------
__global__ __launch_bounds__(256, 2) void gemm_proj(
    const bf16* __restrict__ A, const bf16* __restrict__ W,
    const float* __restrict__ bias, float* __restrict__ out)
{
  constexpr int BM = 64, BN = 128, MI = 2, NJ = 4;
  constexpr int K = 1280, N = 1280;
  constexpr int ASLOT = BM * 32;            // 2048
  constexpr int BSLOT = BN * 32;            // 4096
  __shared__ __align__(16) bf16 smem[4 * (ASLOT + BSLOT)];
  bf16* As = smem;
  bf16* Bs = smem + 4 * ASLOT;

  int tid  = threadIdx.x;
  int wave = tid >> 6, lane = tid & 63;
  int l15 = lane & 15, quad = lane >> 4;
  int q8s = ((quad ^ ((l15 >> 1) & 3)) * 8);
  int tiles_m = 64;                         // 4096/64
  int mt = blockIdx.x % tiles_m;
  int nt = blockIdx.x / tiles_m;
  int m0 = mt * BM, n0 = nt * BN;
  int wm = (wave >> 1) * (BM / 2), wn = (wave & 1) * (BN / 2);

  int er  = tid >> 2;
  int ec8 = (((tid & 3) ^ ((tid >> 3) & 3)) * 8);
  const bf16* ga = A + (size_t)(m0 + er) * K + ec8;
  const bf16* gb = W + (size_t)(n0 + er) * K + ec8;

  auto issueN = [&](int k, int s) {        // 3 VMEM instrs per thread
    bf16* la = As + s * ASLOT + tid * 8;
    bf16* lb = Bs + s * BSLOT + tid * 8;
    gload16(ga + k, la);
    gload16(gb + k, lb);
    gload16(gb + (size_t)64 * K + k, lb + 2048);
  };

  f32x4 acc[MI][NJ];
#pragma unroll
  for (int i = 0; i < MI; ++i)
#pragma unroll
    for (int j = 0; j < NJ; ++j) acc[i][j] = (f32x4){0.f, 0.f, 0.f, 0.f};

  constexpr int NK = K / 32;               // 40
  issueN(0, 0);
  issueN(32, 1);
  for (int kt = 0; kt < NK; ++kt) {
    int p = kt & 3;
    if (kt + 2 < NK) {
      issueN((kt + 2) * 32, (kt + 2) & 3);
      WAITVM(6);                           // tile kt landed; kt+1,kt+2 fly
    } else if (kt + 1 < NK) {
      WAITVM(3);
    } else {
      WAITVM(0);
    }
    SBAR();
    bf16x8 af[MI], bfr[NJ];
#pragma unroll
    for (int i = 0; i < MI; ++i)
      af[i] = *(const bf16x8*)(As + p * ASLOT + (wm + i * 16 + l15) * 32 + q8s);
#pragma unroll
    for (int j = 0; j < NJ; ++j)
      bfr[j] = *(const bf16x8*)(Bs + p * BSLOT + (wn + j * 16 + l15) * 32 + q8s);
    __builtin_amdgcn_s_setprio(1);
#pragma unroll
    for (int i = 0; i < MI; ++i)
#pragma unroll
      for (int j = 0; j < NJ; ++j)
        acc[i][j] = __builtin_amdgcn_mfma_f32_16x16x32_bf16(af[i], bfr[j], acc[i][j], 0, 0, 0);
    __builtin_amdgcn_s_setprio(0);
  }

#pragma unroll
  for (int j = 0; j < NJ; ++j) {
    int col = n0 + wn + j * 16 + l15;
    float bv = bias[col];
#pragma unroll
    for (int i = 0; i < MI; ++i)
#pragma unroll
      for (int r = 0; r < 4; ++r) {
        int row = m0 + wm + i * 16 + quad * 4 + r;
        out[(size_t)row * N + col] = acc[i][j][r] + bv;
      }
  }
}

// ---------------------------------------------------------------------------
extern "C" void kernel_launch(void* const* d_in, const int* in_sizes, int n_in,
                              void* d_out, int out_size, void* d_ws, size_t ws_size,
                              hipStream_t stream)
{
  const float* hidden = (const float*)d_in[0];
  // d_in[1]: cu_seqlens (int32) — fixed 8x512 segments, handled structurally
  const float* rot    = (const float*)d_in[2];
  const float* qkv_w  = (const float*)d_in[3];
  const float* qkv_b  = (const float*)d_in[4];
  const float* proj_w = (const float*)d_in[5];
  const float* proj_b = (const float*)d_in[6];
  float* out = (float*)d_out;

  char* ws = (char*)d_ws;
  bf16* qkvw_bf  = (bf16*)(ws);              //  9,830,400 B [3840][1280]
  bf16* projw_bf = (bf16*)(ws +  9830400);   //  3,276,800 B [1280][1280]
  bf16* hid_bf   = (bf16*)(ws + 13107200);   // 10,485,760 B [4096][1280]
  bf16* attn     = (bf16*)(ws + 13107200);   // reuses hid_bf (dead after K1)
  bf16* Qh       = (bf16*)(ws + 23592960);   // 12,582,912 B [16][4096][96]
  bf16* Kh       = (bf16*)(ws + 36175872);   // 12,582,912 B
  bf16* Vt       = (bf16*)(ws + 48758784);   // 10,485,760 B [16][80][4096]
                                             // total 59,244,544 B

  cvt_all<<<dim3(11520), dim3(256), 0, stream>>>(
      hidden, qkv_w, proj_w, hid_bf, qkvw_bf, projw_bf);
  // K1: qkv GEMM + fused rope, 32x24 tiles of 128x160, XCD = nt%8 mapping
  gemm_qkv<<<dim3(768), dim3(256), 0, stream>>>(
      hid_bf, qkvw_bf, qkv_b, rot, Qh, Kh, Vt);
  // K3: block-diagonal attention, group->XCD co-located grid
  attn_kernel<<<dim3(1024), dim3(256), 0, stream>>>(Qh, Kh, Vt, attn);
  // K4: proj GEMM, 64x10 tiles of 64x128, ring + counted vmcnt
  gemm_proj<<<dim3(640), dim3(256), 0, stream>>>(
      attn, projw_bf, proj_b, out);
}

// Round 6
// 205.979 us; speedup vs baseline: 1.0668x; 1.0668x over previous
//
#include <hip/hip_runtime.h>
#include <hip/hip_bf16.h>

// ---------------------------------------------------------------------------
// Qwen2VL SDPA attention block, MI355X/gfx950. fp32 in/out, bf16 MFMA inside.
// T=4096, D=1280, H=16, HD=80, 8 segments of 512 (block-diagonal attention).
// Pipeline: [C]  convert hidden/qkv_w/proj_w fp32->bf16 (one fused kernel)
//           [K1] gemm_qkv: 128x160 tile, 2-phase dbuf global_load_lds,
//                (256,4), XCD map; FUSED ROPE epilogue -> Qh/Kh [h][t][96],
//                V -> Vt[h][d][t]   (measured 62 us)
//           [K3] attention: K/V DMA-staged double buffers, exact softmax,
//                setprio on MFMA clusters (the version in both 205-us totals)
//           [K4] gemm_proj: 64x128 tile, 4-slot ring, counted vmcnt
//                (measured -19 us vs 2-phase via R2/R4 budget delta)
// Session ledger:
//  R1 swizzle: conflicts 4.4M->0, -4% (not conflict-bound)
//  R2 XCD map + 4/CU: FETCH at floor, flat (schedule-bound)
//  R3 counted-vmcnt + tight reg bound: acc spilled, 5x blowup (reverted)
//  R4 4-slot ring everywhere: K1 80us (occupancy loss) but K4 -19us (kept)
//  R5 K3 L2-direct phase A: +32us (4x L2 re-read + latency-exposed gathers;
//     intra-block 4-wave reuse NEEDS the LDS stage) -> reverted here.
// ---------------------------------------------------------------------------

#define T_DIM 4096
#define D_DIM 1280
#define NH    16
#define HD    80
#define HDP   96      // head dim padded to 3x32 for K=32 MFMA steps
#define SEG   512
#define VLP   136     // P LDS row stride (pad off pow2)
#define RLS   80      // rope-epilogue LDS row stride

typedef __bf16 bf16;
typedef bf16  bf16x4 __attribute__((ext_vector_type(4)));
typedef bf16  bf16x8 __attribute__((ext_vector_type(8)));
typedef float f32x4  __attribute__((ext_vector_type(4)));

#define WAITVM(n) asm volatile("s_waitcnt vmcnt(" #n ")" ::: "memory")
#define SBAR()    asm volatile("s_barrier" ::: "memory")

__device__ __forceinline__ void gload16(const bf16* g, bf16* l) {
  __builtin_amdgcn_global_load_lds(
      (const __attribute__((address_space(1))) void*)g,
      (__attribute__((address_space(3))) void*)l, 16, 0, 0);
}

// ---------------------------------------------------------------------------
// Fused fp32->bf16 convert of hidden (1310720 f4), qkv_w (1228800 f4),
// proj_w (409600 f4). Grid covers 2949120 float4 groups.
// ---------------------------------------------------------------------------
__global__ __launch_bounds__(256) void cvt_all(
    const float* __restrict__ hid, const float* __restrict__ qw,
    const float* __restrict__ pw, bf16* __restrict__ hb,
    bf16* __restrict__ qwb, bf16* __restrict__ pwb)
{
  int i = blockIdx.x * 256 + threadIdx.x;
  const float* src; bf16* dst; int off;
  if (i < 1310720)      { src = hid; dst = hb;  off = i; }
  else if (i < 2539520) { src = qw;  dst = qwb; off = i - 1310720; }
  else                  { src = pw;  dst = pwb; off = i - 2539520; }
  float4 v = ((const float4*)src)[off];
  ((bf16x4*)dst)[off] = (bf16x4){(bf16)v.x, (bf16)v.y, (bf16)v.z, (bf16)v.w};
}

// ---------------------------------------------------------------------------
// K1: qkv GEMM, BM=128 BN=160 BK=32, 4 waves (2x2), wave = 64x80 (one head
// per wave-half). 2-phase dbuf via global_load_lds; __syncthreads drains.
// LDS rows 32 bf16 = 4 chunks of 16 B, chunk c of row r holds logical chunk
// c ^ ((r>>1)&3) (pre-swizzled global source, deswizzled frag read).
// Grid: mt=lin/24, nt=lin%24 (24%8==0 => XCD=nt%8, W-tile L2-resident).
// Epilogue: Q/K -> wave LDS -> rope -> [h][t][96] chunks XOR-swizzled by
// ((t>>1)&3); V -> Vt[h][d][T] bf16x4 scatter.
// ---------------------------------------------------------------------------
__global__ __launch_bounds__(256, 4) void gemm_qkv(
    const bf16* __restrict__ A, const bf16* __restrict__ W,
    const float* __restrict__ bias, const float* __restrict__ rot,
    bf16* __restrict__ Qh, bf16* __restrict__ Kh, bf16* __restrict__ Vt)
{
  constexpr int BM = 128, BN = 160, MI = 4, NJ = 5;
  constexpr int K = 1280;
  constexpr int STAGE = 2 * (BM + BN) * 32;       // 18432 elems
  constexpr int EPIB  = 4 * 64 * RLS;             // 20480 elems
  constexpr int LDSZ  = (STAGE > EPIB ? STAGE : EPIB);
  __shared__ __align__(16) bf16 smem[LDSZ];
  bf16* As = smem;
  bf16* Bs = smem + 2 * BM * 32;

  int tid  = threadIdx.x;
  int wave = tid >> 6, lane = tid & 63;
  int l15 = lane & 15, quad = lane >> 4;
  int q8s = ((quad ^ ((l15 >> 1) & 3)) * 8);      // frag-read deswizzle
  int mt = blockIdx.x / 24;
  int nt = blockIdx.x % 24;
  int m0 = mt * BM, n0 = nt * BN;
  int wm = (wave >> 1) * (BM / 2), wn = (wave & 1) * (BN / 2);

  int er  = tid >> 2;
  int ec8 = (((tid & 3) ^ ((tid >> 3) & 3)) * 8); // source pre-swizzle
  const bf16* ga = A + (size_t)(m0 + er) * K + ec8;
  const bf16* gb = W + (size_t)(n0 + er) * K + ec8;

  // staging: A 128 rows (2 chunks/thread), B 160 rows (2 + tid<128 third)
  auto issueN = [&](int k, int p) {
    bf16* la = As + p * (BM * 32) + tid * 8;
    bf16* lb = Bs + p * (BN * 32) + tid * 8;
    gload16(ga + k, la);
    gload16(ga + (size_t)64 * K + k, la + 2048);
    gload16(gb + k, lb);
    gload16(gb + (size_t)64 * K + k, lb + 2048);
    if (tid < 128) gload16(gb + (size_t)128 * K + k, lb + 4096);
  };

  f32x4 acc[MI][NJ];
#pragma unroll
  for (int i = 0; i < MI; ++i)
#pragma unroll
    for (int j = 0; j < NJ; ++j) acc[i][j] = (f32x4){0.f, 0.f, 0.f, 0.f};

  constexpr int NK = K / 32;
  issueN(0, 0);
  for (int kt = 0; kt < NK; ++kt) {
    int p = kt & 1;
    __syncthreads();                      // drains DMA(kt) + prev frag reads
    if (kt + 1 < NK) issueN((kt + 1) * 32, p ^ 1);
    bf16x8 af[MI], bfr[NJ];
#pragma unroll
    for (int i = 0; i < MI; ++i)
      af[i] = *(const bf16x8*)(As + p * (BM * 32) + (wm + i * 16 + l15) * 32 + q8s);
#pragma unroll
    for (int j = 0; j < NJ; ++j)
      bfr[j] = *(const bf16x8*)(Bs + p * (BN * 32) + (wn + j * 16 + l15) * 32 + q8s);
#pragma unroll
    for (int i = 0; i < MI; ++i)
#pragma unroll
      for (int j = 0; j < NJ; ++j)
        acc[i][j] = __builtin_amdgcn_mfma_f32_16x16x32_bf16(af[i], bfr[j], acc[i][j], 0, 0, 0);
  }

  int c0  = n0 + wn;                 // wave's first col = head base
  int sel = c0 / D_DIM;              // 0=Q, 1=K, 2=V (block-uniform)
  if (sel < 2) {
    // ---- fused rope epilogue ----
    __syncthreads();                 // all frag reads done; reuse smem
    bf16* Lw = smem + wave * (64 * RLS);
    int cc0 = c0 - sel * D_DIM;
    int h   = cc0 / HD;
#pragma unroll
    for (int j = 0; j < NJ; ++j) {
      float bv = bias[c0 + j * 16 + l15];
#pragma unroll
      for (int i = 0; i < MI; ++i)
#pragma unroll
        for (int r = 0; r < 4; ++r)
          Lw[(i * 16 + quad * 4 + r) * RLS + j * 16 + l15] = (bf16)(acc[i][j][r] + bv);
    }
    __syncthreads();
    int t = m0 + wm + lane;          // lane = local row
    bf16x4 x[20];
#pragma unroll
    for (int a = 0; a < 20; ++a)
      x[a] = *(const bf16x4*)(Lw + lane * RLS + a * 4);
    const float* fp = rot + t * 40;
    float fr[40];
#pragma unroll
    for (int a = 0; a < 10; ++a) {
      float4 f4 = *(const float4*)(fp + a * 4);
      fr[a * 4] = f4.x; fr[a * 4 + 1] = f4.y; fr[a * 4 + 2] = f4.z; fr[a * 4 + 3] = f4.w;
    }
    const float sc = (sel == 0) ? 0.11180339887498949f : 1.0f;
    bf16* dst = ((sel == 0) ? Qh : Kh) + ((size_t)h * T_DIM + t) * HDP;
    int ksw = (t >> 1) & 3;          // row chunk swizzle
#pragma unroll
    for (int g = 0; g < 5; ++g) {
      bf16x8 c1, c2;
#pragma unroll
      for (int bb = 0; bb < 8; ++bb) {
        int a = g * 2 + (bb >> 2), b = bb & 3;
        float cs, sn;
        __sincosf(fr[a * 4 + b], &sn, &cs);
        cs *= sc; sn *= sc;
        float xa = (float)x[a][b], xb = (float)x[a + 10][b];
        c1[bb] = (bf16)(xa * cs - xb * sn);
        c2[bb] = (bf16)(xb * cs + xa * sn);
      }
      *(bf16x8*)(dst + (g ^ ksw) * 8)       = c1;
      *(bf16x8*)(dst + ((g + 5) ^ ksw) * 8) = c2;
    }
    bf16x8 z = {};
    *(bf16x8*)(dst + (10 ^ ksw) * 8) = z;
    *(bf16x8*)(dst + (11 ^ ksw) * 8) = z;
  } else {
    // ---- V scatter (transposed, t-major) ----
#pragma unroll
    for (int j = 0; j < NJ; ++j) {
      int c = c0 + j * 16 + l15;
      float bv = bias[c];
      int cc = c - 2 * D_DIM;
      int h = cc / HD, d = cc - h * HD;
      bf16* vrow = Vt + ((size_t)h * HD + d) * T_DIM;
#pragma unroll
      for (int i = 0; i < MI; ++i) {
        int t0 = m0 + wm + i * 16 + quad * 4;
        bf16x4 pv = {(bf16)(acc[i][j][0] + bv), (bf16)(acc[i][j][1] + bv),
                     (bf16)(acc[i][j][2] + bv), (bf16)(acc[i][j][3] + bv)};
        *(bf16x4*)(vrow + t0) = pv;
      }
    }
  }
}

// ---------------------------------------------------------------------------
// K3: attention (staged form — the one inside both 205-us totals).
// Grid 1024; all 8 tiles of (seg,head) group g land on XCD g%8 (128%8==0)
// => K/V L2-resident. K/V staged via global_load_lds into double buffers;
// one barrier per QK chunk; V(0) prefetch issued during the last QK chunk
// and drains behind the softmax VALU stretch. V chunks XOR-swizzled
// (chunk ^ (d&7)). Qh/Kh rows arrive chunk-swizzled by ((t>>1)&3) (from
// K1); qf/kb deswizzle. s_setprio(1) around MFMA clusters.
// ---------------------------------------------------------------------------
__global__ __launch_bounds__(256, 2) void attn_kernel(
    const bf16* __restrict__ Qh, const bf16* __restrict__ Kh,
    const bf16* __restrict__ Vt, bf16* __restrict__ out)
{
  // KV double buffers 2 x 24576 B (K [128][96] / V [80][128]); P 17408 B
  __shared__ __align__(16) char smem[66560];
  bf16* KV[2] = {(bf16*)smem, (bf16*)(smem + 24576)};
  bf16* Pl    = (bf16*)(smem + 49152);

  int lin  = blockIdx.x;
  int g    = lin & 127;        // (seg,head) group
  int tile = lin >> 7;         // 0..7
  int h    = g & 15;
  int seg  = g >> 4;
  int seg0 = seg * SEG;
  int t0   = seg0 + tile * 64;

  int tid  = threadIdx.x;
  int wave = tid >> 6;
  int lane = tid & 63;
  int l15 = lane & 15, quad = lane >> 4, q8 = quad * 8;
  int qs8 = ((quad ^ ((l15 >> 1) & 3)) * 8);   // Qh/Kh chunk deswizzle
  int tw = t0 + wave * 16;

  const bf16* khbase = Kh + ((size_t)h * T_DIM + seg0) * HDP;
  const bf16* vtbase = Vt + (size_t)h * HD * T_DIM + seg0;

  auto issueK = [&](int kc, bf16* buf) {
    const bf16* src = khbase + (size_t)kc * (128 * HDP);
#pragma unroll
    for (int i = 0; i < 6; ++i)
      gload16(src + (i * 256 + tid) * 8, buf + (i * 256 + tid) * 8);
  };
  auto issueV = [&](int kc, bf16* buf) {
    const bf16* src = vtbase + kc * 128;
#pragma unroll
    for (int i = 0; i < 5; ++i) {
      int idx = i * 256 + tid;            // 0..1279
      int d = idx >> 4, ch = idx & 15;
      int chg = ch ^ (d & 7);             // XOR source-chunk swizzle
      gload16(src + (size_t)d * T_DIM + chg * 8, buf + idx * 8);
    }
  };

  issueK(0, KV[0]);

  bf16x8 qf[3];
  {
    const bf16* qbase = Qh + ((size_t)h * T_DIM + tw + l15) * HDP + qs8;
#pragma unroll
    for (int kk = 0; kk < 3; ++kk) qf[kk] = *(const bf16x8*)(qbase + kk * 32);
  }

  // ---- Phase A: S = Q K^T, 4 chunks of 128 keys, 1 barrier/chunk ----
  f32x4 S[4][8];
  for (int kc = 0; kc < 4; ++kc) {
    bf16* buf = KV[kc & 1];
    __syncthreads();                       // drains DMA(kc) + prior reads
    if (kc < 3) issueK(kc + 1, KV[(kc & 1) ^ 1]);
    else        issueV(0, KV[0]);          // KV[0] free (last read chunk 2)
    __builtin_amdgcn_s_setprio(1);
#pragma unroll
    for (int j = 0; j < 8; ++j) {
      f32x4 acc = {0.f, 0.f, 0.f, 0.f};
      const bf16* kb = buf + (j * 16 + l15) * HDP + qs8;
#pragma unroll
      for (int kk = 0; kk < 3; ++kk)
        acc = __builtin_amdgcn_mfma_f32_16x16x32_bf16(qf[kk], *(const bf16x8*)(kb + kk * 32), acc, 0, 0, 0);
      S[kc][j] = acc;
    }
    __builtin_amdgcn_s_setprio(0);
  }

  // ---- Softmax (exact; scale pre-folded into Q). V(0) in flight. ----
  float vsum[4];
#pragma unroll
  for (int r = 0; r < 4; ++r) {
    float m = -1e30f;
#pragma unroll
    for (int kc = 0; kc < 4; ++kc)
#pragma unroll
      for (int j = 0; j < 8; ++j) m = fmaxf(m, S[kc][j][r]);
    for (int off = 1; off < 16; off <<= 1) m = fmaxf(m, __shfl_xor(m, off));
    float s = 0.f;
#pragma unroll
    for (int kc = 0; kc < 4; ++kc)
#pragma unroll
      for (int j = 0; j < 8; ++j) {
        float e = __expf(S[kc][j][r] - m);
        S[kc][j][r] = e;
        s += e;
      }
    for (int off = 1; off < 16; off <<= 1) s += __shfl_xor(s, off);
    vsum[r] = s;
  }

  // ---- Phase B: O = P V, 4 chunks, V prefetched one chunk ahead ----
  f32x4 O[5];
#pragma unroll
  for (int n = 0; n < 5; ++n) O[n] = (f32x4){0.f, 0.f, 0.f, 0.f};
  bf16* Plw = Pl + wave * (16 * VLP);

  for (int kc = 0; kc < 4; ++kc) {
    bf16* vbuf = KV[kc & 1];
    __syncthreads();                       // drains V(kc); prior MFMA reads done
    if (kc < 3) issueV(kc + 1, KV[(kc & 1) ^ 1]);
#pragma unroll
    for (int j = 0; j < 8; ++j)
#pragma unroll
      for (int r = 0; r < 4; ++r)
        Plw[(quad * 4 + r) * VLP + j * 16 + l15] = (bf16)S[kc][j][r];
    __syncthreads();                       // P visible
    __builtin_amdgcn_s_setprio(1);
#pragma unroll
    for (int ks = 0; ks < 4; ++ks) {
      bf16x8 pa = *(const bf16x8*)(Plw + l15 * VLP + ks * 32 + q8);
#pragma unroll
      for (int n = 0; n < 5; ++n) {
        int d = n * 16 + l15;
        // global chunk (ks*4+quad) lives at LDS chunk ^(d&7)
        int chl = (ks * 4 + quad) ^ (d & 7);
        bf16x8 vb = *(const bf16x8*)(vbuf + d * 128 + chl * 8);
        O[n] = __builtin_amdgcn_mfma_f32_16x16x32_bf16(pa, vb, O[n], 0, 0, 0);
      }
    }
    __builtin_amdgcn_s_setprio(0);
  }

#pragma unroll
  for (int n = 0; n < 5; ++n)
#pragma unroll
    for (int r = 0; r < 4; ++r) {
      int row = tw + quad * 4 + r;
      int col = h * HD + n * 16 + l15;
      out[(size_t)row * D_DIM + col] = (bf16)(O[n][r] / vsum[r]);
    }
}

// ---------------------------------------------------------------------------
// K4: proj GEMM, BM=64 BN=128 BK=32, 4 waves, wave = 32x64 (MI=2, NJ=4).
// 4-slot LDS ring, counted vmcnt (issue kt+2; wait vmcnt(6) => tiles kt+1,
// kt+2 in flight, tile kt landed; ONE s_barrier/iter). 49152 B LDS =>
// 3 blocks/CU. fp32 out + bias. A-sharing XCD swizzle (lin%8 == mt%8).
// ---------------------------------------------------------------------------
__global__ __launch_bounds__(256, 2) void gemm_proj(
    const bf16* __restrict__ A, const bf16* __restrict__ W,
    const float* __restrict__ bias, float* __restrict__ out)
{
  constexpr int BM = 64, BN = 128, MI = 2, NJ = 4;
  constexpr int K = 1280, N = 1280;
  constexpr int ASLOT = BM * 32;            // 2048
  constexpr int BSLOT = BN * 32;            // 4096
  __shared__ __align__(16) bf16 smem[4 * (ASLOT + BSLOT)];
  bf16* As = smem;
  bf16* Bs = smem + 4 * ASLOT;

  int tid  = threadIdx.x;
  int wave = tid >> 6, lane = tid & 63;
  int l15 = lane & 15, quad = lane >> 4;
  int q8s = ((quad ^ ((l15 >> 1) & 3)) * 8);
  int tiles_m = 64;                         // 4096/64
  int mt = blockIdx.x % tiles_m;
  int nt = blockIdx.x / tiles_m;
  int m0 = mt * BM, n0 = nt * BN;
  int wm = (wave >> 1) * (BM / 2), wn = (wave & 1) * (BN / 2);

  int er  = tid >> 2;
  int ec8 = (((tid & 3) ^ ((tid >> 3) & 3)) * 8);
  const bf16* ga = A + (size_t)(m0 + er) * K + ec8;
  const bf16* gb = W + (size_t)(n0 + er) * K + ec8;

  auto issueN = [&](int k, int s) {        // 3 VMEM instrs per thread
    bf16* la = As + s * ASLOT + tid * 8;
    bf16* lb = Bs + s * BSLOT + tid * 8;
    gload16(ga + k, la);
    gload16(gb + k, lb);
    gload16(gb + (size_t)64 * K + k, lb + 2048);
  };

  f32x4 acc[MI][NJ];
#pragma unroll
  for (int i = 0; i < MI; ++i)
#pragma unroll
    for (int j = 0; j < NJ; ++j) acc[i][j] = (f32x4){0.f, 0.f, 0.f, 0.f};

  constexpr int NK = K / 32;               // 40
  issueN(0, 0);
  issueN(32, 1);
  for (int kt = 0; kt < NK; ++kt) {
    int p = kt & 3;
    if (kt + 2 < NK) {
      issueN((kt + 2) * 32, (kt + 2) & 3);
      WAITVM(6);                           // tile kt landed; kt+1,kt+2 fly
    } else if (kt + 1 < NK) {
      WAITVM(3);
    } else {
      WAITVM(0);
    }
    SBAR();
    bf16x8 af[MI], bfr[NJ];
#pragma unroll
    for (int i = 0; i < MI; ++i)
      af[i] = *(const bf16x8*)(As + p * ASLOT + (wm + i * 16 + l15) * 32 + q8s);
#pragma unroll
    for (int j = 0; j < NJ; ++j)
      bfr[j] = *(const bf16x8*)(Bs + p * BSLOT + (wn + j * 16 + l15) * 32 + q8s);
    __builtin_amdgcn_s_setprio(1);
#pragma unroll
    for (int i = 0; i < MI; ++i)
#pragma unroll
      for (int j = 0; j < NJ; ++j)
        acc[i][j] = __builtin_amdgcn_mfma_f32_16x16x32_bf16(af[i], bfr[j], acc[i][j], 0, 0, 0);
    __builtin_amdgcn_s_setprio(0);
  }

#pragma unroll
  for (int j = 0; j < NJ; ++j) {
    int col = n0 + wn + j * 16 + l15;
    float bv = bias[col];
#pragma unroll
    for (int i = 0; i < MI; ++i)
#pragma unroll
      for (int r = 0; r < 4; ++r) {
        int row = m0 + wm + i * 16 + quad * 4 + r;
        out[(size_t)row * N + col] = acc[i][j][r] + bv;
      }
  }
}

// ---------------------------------------------------------------------------
extern "C" void kernel_launch(void* const* d_in, const int* in_sizes, int n_in,
                              void* d_out, int out_size, void* d_ws, size_t ws_size,
                              hipStream_t stream)
{
  const float* hidden = (const float*)d_in[0];
  // d_in[1]: cu_seqlens (int32) — fixed 8x512 segments, handled structurally
  const float* rot    = (const float*)d_in[2];
  const float* qkv_w  = (const float*)d_in[3];
  const float* qkv_b  = (const float*)d_in[4];
  const float* proj_w = (const float*)d_in[5];
  const float* proj_b = (const float*)d_in[6];
  float* out = (float*)d_out;

  char* ws = (char*)d_ws;
  bf16* qkvw_bf  = (bf16*)(ws);              //  9,830,400 B [3840][1280]
  bf16* projw_bf = (bf16*)(ws +  9830400);   //  3,276,800 B [1280][1280]
  bf16* hid_bf   = (bf16*)(ws + 13107200);   // 10,485,760 B [4096][1280]
  bf16* attn     = (bf16*)(ws + 13107200);   // reuses hid_bf (dead after K1)
  bf16* Qh       = (bf16*)(ws + 23592960);   // 12,582,912 B [16][4096][96]
  bf16* Kh       = (bf16*)(ws + 36175872);   // 12,582,912 B
  bf16* Vt       = (bf16*)(ws + 48758784);   // 10,485,760 B [16][80][4096]
                                             // total 59,244,544 B

  cvt_all<<<dim3(11520), dim3(256), 0, stream>>>(
      hidden, qkv_w, proj_w, hid_bf, qkvw_bf, projw_bf);
  // K1: qkv GEMM + fused rope, 32x24 tiles of 128x160, XCD = nt%8 mapping
  gemm_qkv<<<dim3(768), dim3(256), 0, stream>>>(
      hid_bf, qkvw_bf, qkv_b, rot, Qh, Kh, Vt);
  // K3: block-diagonal attention, group->XCD co-located grid
  attn_kernel<<<dim3(1024), dim3(256), 0, stream>>>(Qh, Kh, Vt, attn);
  // K4: proj GEMM, 64x10 tiles of 64x128, ring + counted vmcnt
  gemm_proj<<<dim3(640), dim3(256), 0, stream>>>(
      attn, projw_bf, proj_b, out);
}

// Round 7
// 204.582 us; speedup vs baseline: 1.0741x; 1.0068x over previous
//
#include <hip/hip_runtime.h>
#include <hip/hip_bf16.h>

// ---------------------------------------------------------------------------
// Qwen2VL SDPA attention block, MI355X/gfx950. fp32 in/out, bf16 MFMA inside.
// T=4096, D=1280, H=16, HD=80, 8 segments of 512 (block-diagonal attention).
// Pipeline: [C]  convert hidden/qkv_w/proj_w fp32->bf16 (one fused kernel)
//           [K1] gemm_qkv: 128x160 tile, asymmetric ring (A 3-slot, B 2-slot)
//                counted vmcnt, ONE s_barrier/iter, 45056 B LDS = 3 blocks/CU;
//                FUSED ROPE epilogue -> Qh/Kh [h][t][96], V -> Vt[h][d][t]
//           [K3] attention: K/V DMA-staged double buffers, exact softmax
//           [K4] gemm_proj: 64x128 tile, 4-slot ring, counted vmcnt
// Ledger: R1 swizzle (conflicts->0, -4%); R2 XCD map (FETCH at floor, flat);
//  R3 counted-vmcnt+128-reg cap -> acc spill disaster; R4 symmetric ring
//  82KB -> 2/CU -> K1 80us; R5 K3 L2-direct +14us total (reverted); R6
//  recompose = 206 (cross-round budget attribution retired).
// R7 theory: K1 iteration time == DMA latency (~3700cyc; no pipe >30% busy;
//  2-slot dbuf caps latency cover at one compute phase ~500cyc). Fix: A gets
//  3 slots (2-iter cover, it's the L3/HBM-latency stream), B 2 slots (W is
//  XCD-L2-resident, 1-phase cover enough). 45056 B keeps 3 blocks/CU.
//  Stream order B(kt) before A(kt+1) + in-order vmcnt retirement => WAITVM(2)
//  proves tile kt landed for every wave before the single barrier.
// ---------------------------------------------------------------------------

#define T_DIM 4096
#define D_DIM 1280
#define NH    16
#define HD    80
#define HDP   96      // head dim padded to 3x32 for K=32 MFMA steps
#define SEG   512
#define VLP   136     // P LDS row stride (pad off pow2)
#define RLS   80      // rope-epilogue LDS row stride

typedef __bf16 bf16;
typedef bf16  bf16x4 __attribute__((ext_vector_type(4)));
typedef bf16  bf16x8 __attribute__((ext_vector_type(8)));
typedef float f32x4  __attribute__((ext_vector_type(4)));

#define WAITVM(n) asm volatile("s_waitcnt vmcnt(" #n ")" ::: "memory")
#define SBAR()    asm volatile("s_barrier" ::: "memory")

__device__ __forceinline__ void gload16(const bf16* g, bf16* l) {
  __builtin_amdgcn_global_load_lds(
      (const __attribute__((address_space(1))) void*)g,
      (__attribute__((address_space(3))) void*)l, 16, 0, 0);
}

// ---------------------------------------------------------------------------
// Fused fp32->bf16 convert of hidden (1310720 f4), qkv_w (1228800 f4),
// proj_w (409600 f4). Grid covers 2949120 float4 groups.
// ---------------------------------------------------------------------------
__global__ __launch_bounds__(256) void cvt_all(
    const float* __restrict__ hid, const float* __restrict__ qw,
    const float* __restrict__ pw, bf16* __restrict__ hb,
    bf16* __restrict__ qwb, bf16* __restrict__ pwb)
{
  int i = blockIdx.x * 256 + threadIdx.x;
  const float* src; bf16* dst; int off;
  if (i < 1310720)      { src = hid; dst = hb;  off = i; }
  else if (i < 2539520) { src = qw;  dst = qwb; off = i - 1310720; }
  else                  { src = pw;  dst = pwb; off = i - 2539520; }
  float4 v = ((const float4*)src)[off];
  ((bf16x4*)dst)[off] = (bf16x4){(bf16)v.x, (bf16)v.y, (bf16)v.z, (bf16)v.w};
}

// ---------------------------------------------------------------------------
// K1: qkv GEMM, BM=128 BN=160 BK=32, 4 waves (2x2), wave = 64x80 (one head
// per wave-half). Asymmetric staging ring: A 3 slots / B 2 slots via
// global_load_lds; per iter: WAITVM(2) -> SBAR -> issueB(kt+1) ->
// issueA(kt+2) -> frag reads -> MFMA. In-order vmcnt retirement + B-first
// stream order => vmcnt<=2 proves A(kt),B(kt) landed (suffix = A(kt+1)).
// Slot overwritten at iter kt was last read at iter kt-1 (3-slot A:
// (kt+2)%3 == (kt-1)%3; 2-slot B: (kt+1)&1 == (kt-1)&1), SBAR(kt) separates.
// LDS rows 32 bf16 = 4 chunks of 16 B, chunk c of row r holds logical chunk
// c ^ ((r>>1)&3) (pre-swizzled global source, deswizzled frag read).
// Grid: mt=lin/24, nt=lin%24 (24%8==0 => XCD=nt%8, W-tile L2-resident).
// Epilogue: Q/K -> wave LDS -> rope -> [h][t][96] chunks XOR-swizzled by
// ((t>>1)&3); V -> Vt[h][d][T] bf16x4 scatter.
// ---------------------------------------------------------------------------
__global__ __launch_bounds__(256, 3) void gemm_qkv(
    const bf16* __restrict__ A, const bf16* __restrict__ W,
    const float* __restrict__ bias, const float* __restrict__ rot,
    bf16* __restrict__ Qh, bf16* __restrict__ Kh, bf16* __restrict__ Vt)
{
  constexpr int BM = 128, BN = 160, MI = 4, NJ = 5;
  constexpr int K = 1280;
  constexpr int ASLOT = BM * 32;                  // 4096 elems / slot
  constexpr int BSLOT = BN * 32;                  // 5120 elems / slot
  constexpr int STAGE = 3 * ASLOT + 2 * BSLOT;    // 22528 elems = 45056 B
  constexpr int EPIB  = 4 * 64 * RLS;             // 20480 elems
  constexpr int LDSZ  = (STAGE > EPIB ? STAGE : EPIB);
  __shared__ __align__(16) bf16 smem[LDSZ];
  bf16* As = smem;                                // 3 slots
  bf16* Bs = smem + 3 * ASLOT;                    // 2 slots

  int tid  = threadIdx.x;
  int wave = tid >> 6, lane = tid & 63;
  int l15 = lane & 15, quad = lane >> 4;
  int q8s = ((quad ^ ((l15 >> 1) & 3)) * 8);      // frag-read deswizzle
  int mt = blockIdx.x / 24;
  int nt = blockIdx.x % 24;
  int m0 = mt * BM, n0 = nt * BN;
  int wm = (wave >> 1) * (BM / 2), wn = (wave & 1) * (BN / 2);

  int er  = tid >> 2;
  int ec8 = (((tid & 3) ^ ((tid >> 3) & 3)) * 8); // source pre-swizzle
  const bf16* ga = A + (size_t)(m0 + er) * K + ec8;
  const bf16* gb = W + (size_t)(n0 + er) * K + ec8;

  // A batch: 2 VMEM instr/thread (uniform). B batch: 3 (waves 0-1) / 2 (2-3).
  auto issueA = [&](int k, int s) {
    bf16* la = As + s * ASLOT + tid * 8;
    gload16(ga + k, la);
    gload16(ga + (size_t)64 * K + k, la + 2048);
  };
  auto issueB = [&](int k, int s) {
    bf16* lb = Bs + s * BSLOT + tid * 8;
    gload16(gb + k, lb);
    gload16(gb + (size_t)64 * K + k, lb + 2048);
    if (tid < 128) gload16(gb + (size_t)128 * K + k, lb + 4096);
  };

  f32x4 acc[MI][NJ];
#pragma unroll
  for (int i = 0; i < MI; ++i)
#pragma unroll
    for (int j = 0; j < NJ; ++j) acc[i][j] = (f32x4){0.f, 0.f, 0.f, 0.f};

  constexpr int NK = K / 32;                      // 40
  // prologue stream: A(0), B(0), A(1)  (keeps "A(t) before B(t)" order)
  issueA(0, 0);
  issueB(0, 0);
  issueA(32, 1);
  for (int kt = 0; kt < NK; ++kt) {
    // newest-needed = B(kt); suffix after it = A(kt+1) (2 instr) or nothing
    if (kt + 1 < NK) { WAITVM(2); } else { WAITVM(0); }
    SBAR();                                       // tile kt visible block-wide;
                                                  // iter kt-1 reads retired
    if (kt + 1 < NK) issueB((kt + 1) * 32, (kt + 1) & 1);
    if (kt + 2 < NK) issueA((kt + 2) * 32, (kt + 2) % 3);
    bf16x8 af[MI], bfr[NJ];
    const bf16* ap = As + (kt % 3) * ASLOT;
    const bf16* bp = Bs + (kt & 1) * BSLOT;
#pragma unroll
    for (int i = 0; i < MI; ++i)
      af[i] = *(const bf16x8*)(ap + (wm + i * 16 + l15) * 32 + q8s);
#pragma unroll
    for (int j = 0; j < NJ; ++j)
      bfr[j] = *(const bf16x8*)(bp + (wn + j * 16 + l15) * 32 + q8s);
#pragma unroll
    for (int i = 0; i < MI; ++i)
#pragma unroll
      for (int j = 0; j < NJ; ++j)
        acc[i][j] = __builtin_amdgcn_mfma_f32_16x16x32_bf16(af[i], bfr[j], acc[i][j], 0, 0, 0);
  }

  int c0  = n0 + wn;                 // wave's first col = head base
  int sel = c0 / D_DIM;              // 0=Q, 1=K, 2=V (block-uniform)
  if (sel < 2) {
    // ---- fused rope epilogue ----
    __syncthreads();                 // all frag reads done; reuse smem
    bf16* Lw = smem + wave * (64 * RLS);
    int cc0 = c0 - sel * D_DIM;
    int h   = cc0 / HD;
#pragma unroll
    for (int j = 0; j < NJ; ++j) {
      float bv = bias[c0 + j * 16 + l15];
#pragma unroll
      for (int i = 0; i < MI; ++i)
#pragma unroll
        for (int r = 0; r < 4; ++r)
          Lw[(i * 16 + quad * 4 + r) * RLS + j * 16 + l15] = (bf16)(acc[i][j][r] + bv);
    }
    __syncthreads();
    int t = m0 + wm + lane;          // lane = local row
    bf16x4 x[20];
#pragma unroll
    for (int a = 0; a < 20; ++a)
      x[a] = *(const bf16x4*)(Lw + lane * RLS + a * 4);
    const float* fp = rot + t * 40;
    float fr[40];
#pragma unroll
    for (int a = 0; a < 10; ++a) {
      float4 f4 = *(const float4*)(fp + a * 4);
      fr[a * 4] = f4.x; fr[a * 4 + 1] = f4.y; fr[a * 4 + 2] = f4.z; fr[a * 4 + 3] = f4.w;
    }
    const float sc = (sel == 0) ? 0.11180339887498949f : 1.0f;
    bf16* dst = ((sel == 0) ? Qh : Kh) + ((size_t)h * T_DIM + t) * HDP;
    int ksw = (t >> 1) & 3;          // row chunk swizzle
#pragma unroll
    for (int g = 0; g < 5; ++g) {
      bf16x8 c1, c2;
#pragma unroll
      for (int bb = 0; bb < 8; ++bb) {
        int a = g * 2 + (bb >> 2), b = bb & 3;
        float cs, sn;
        __sincosf(fr[a * 4 + b], &sn, &cs);
        cs *= sc; sn *= sc;
        float xa = (float)x[a][b], xb = (float)x[a + 10][b];
        c1[bb] = (bf16)(xa * cs - xb * sn);
        c2[bb] = (bf16)(xb * cs + xa * sn);
      }
      *(bf16x8*)(dst + (g ^ ksw) * 8)       = c1;
      *(bf16x8*)(dst + ((g + 5) ^ ksw) * 8) = c2;
    }
    bf16x8 z = {};
    *(bf16x8*)(dst + (10 ^ ksw) * 8) = z;
    *(bf16x8*)(dst + (11 ^ ksw) * 8) = z;
  } else {
    // ---- V scatter (transposed, t-major) ----
#pragma unroll
    for (int j = 0; j < NJ; ++j) {
      int c = c0 + j * 16 + l15;
      float bv = bias[c];
      int cc = c - 2 * D_DIM;
      int h = cc / HD, d = cc - h * HD;
      bf16* vrow = Vt + ((size_t)h * HD + d) * T_DIM;
#pragma unroll
      for (int i = 0; i < MI; ++i) {
        int t0 = m0 + wm + i * 16 + quad * 4;
        bf16x4 pv = {(bf16)(acc[i][j][0] + bv), (bf16)(acc[i][j][1] + bv),
                     (bf16)(acc[i][j][2] + bv), (bf16)(acc[i][j][3] + bv)};
        *(bf16x4*)(vrow + t0) = pv;
      }
    }
  }
}

// ---------------------------------------------------------------------------
// K3: attention (staged form). Grid 1024; all 8 tiles of (seg,head) group g
// land on XCD g%8 => K/V L2-resident. K/V staged via global_load_lds into
// double buffers; one barrier per QK chunk; V(0) prefetch issued during the
// last QK chunk and drains behind the softmax VALU stretch. V chunks
// XOR-swizzled (chunk ^ (d&7)). Qh/Kh rows arrive chunk-swizzled by
// ((t>>1)&3) (from K1); qf/kb deswizzle. s_setprio(1) around MFMA clusters.
// ---------------------------------------------------------------------------
__global__ __launch_bounds__(256, 2) void attn_kernel(
    const bf16* __restrict__ Qh, const bf16* __restrict__ Kh,
    const bf16* __restrict__ Vt, bf16* __restrict__ out)
{
  // KV double buffers 2 x 24576 B (K [128][96] / V [80][128]); P 17408 B
  __shared__ __align__(16) char smem[66560];
  bf16* KV[2] = {(bf16*)smem, (bf16*)(smem + 24576)};
  bf16* Pl    = (bf16*)(smem + 49152);

  int lin  = blockIdx.x;
  int g    = lin & 127;        // (seg,head) group
  int tile = lin >> 7;         // 0..7
  int h    = g & 15;
  int seg  = g >> 4;
  int seg0 = seg * SEG;
  int t0   = seg0 + tile * 64;

  int tid  = threadIdx.x;
  int wave = tid >> 6;
  int lane = tid & 63;
  int l15 = lane & 15, quad = lane >> 4, q8 = quad * 8;
  int qs8 = ((quad ^ ((l15 >> 1) & 3)) * 8);   // Qh/Kh chunk deswizzle
  int tw = t0 + wave * 16;

  const bf16* khbase = Kh + ((size_t)h * T_DIM + seg0) * HDP;
  const bf16* vtbase = Vt + (size_t)h * HD * T_DIM + seg0;

  auto issueK = [&](int kc, bf16* buf) {
    const bf16* src = khbase + (size_t)kc * (128 * HDP);
#pragma unroll
    for (int i = 0; i < 6; ++i)
      gload16(src + (i * 256 + tid) * 8, buf + (i * 256 + tid) * 8);
  };
  auto issueV = [&](int kc, bf16* buf) {
    const bf16* src = vtbase + kc * 128;
#pragma unroll
    for (int i = 0; i < 5; ++i) {
      int idx = i * 256 + tid;            // 0..1279
      int d = idx >> 4, ch = idx & 15;
      int chg = ch ^ (d & 7);             // XOR source-chunk swizzle
      gload16(src + (size_t)d * T_DIM + chg * 8, buf + idx * 8);
    }
  };

  issueK(0, KV[0]);

  bf16x8 qf[3];
  {
    const bf16* qbase = Qh + ((size_t)h * T_DIM + tw + l15) * HDP + qs8;
#pragma unroll
    for (int kk = 0; kk < 3; ++kk) qf[kk] = *(const bf16x8*)(qbase + kk * 32);
  }

  // ---- Phase A: S = Q K^T, 4 chunks of 128 keys, 1 barrier/chunk ----
  f32x4 S[4][8];
  for (int kc = 0; kc < 4; ++kc) {
    bf16* buf = KV[kc & 1];
    __syncthreads();                       // drains DMA(kc) + prior reads
    if (kc < 3) issueK(kc + 1, KV[(kc & 1) ^ 1]);
    else        issueV(0, KV[0]);          // KV[0] free (last read chunk 2)
    __builtin_amdgcn_s_setprio(1);
#pragma unroll
    for (int j = 0; j < 8; ++j) {
      f32x4 acc = {0.f, 0.f, 0.f, 0.f};
      const bf16* kb = buf + (j * 16 + l15) * HDP + qs8;
#pragma unroll
      for (int kk = 0; kk < 3; ++kk)
        acc = __builtin_amdgcn_mfma_f32_16x16x32_bf16(qf[kk], *(const bf16x8*)(kb + kk * 32), acc, 0, 0, 0);
      S[kc][j] = acc;
    }
    __builtin_amdgcn_s_setprio(0);
  }

  // ---- Softmax (exact; scale pre-folded into Q). V(0) in flight. ----
  float vsum[4];
#pragma unroll
  for (int r = 0; r < 4; ++r) {
    float m = -1e30f;
#pragma unroll
    for (int kc = 0; kc < 4; ++kc)
#pragma unroll
      for (int j = 0; j < 8; ++j) m = fmaxf(m, S[kc][j][r]);
    for (int off = 1; off < 16; off <<= 1) m = fmaxf(m, __shfl_xor(m, off));
    float s = 0.f;
#pragma unroll
    for (int kc = 0; kc < 4; ++kc)
#pragma unroll
      for (int j = 0; j < 8; ++j) {
        float e = __expf(S[kc][j][r] - m);
        S[kc][j][r] = e;
        s += e;
      }
    for (int off = 1; off < 16; off <<= 1) s += __shfl_xor(s, off);
    vsum[r] = s;
  }

  // ---- Phase B: O = P V, 4 chunks, V prefetched one chunk ahead ----
  f32x4 O[5];
#pragma unroll
  for (int n = 0; n < 5; ++n) O[n] = (f32x4){0.f, 0.f, 0.f, 0.f};
  bf16* Plw = Pl + wave * (16 * VLP);

  for (int kc = 0; kc < 4; ++kc) {
    bf16* vbuf = KV[kc & 1];
    __syncthreads();                       // drains V(kc); prior MFMA reads done
    if (kc < 3) issueV(kc + 1, KV[(kc & 1) ^ 1]);
#pragma unroll
    for (int j = 0; j < 8; ++j)
#pragma unroll
      for (int r = 0; r < 4; ++r)
        Plw[(quad * 4 + r) * VLP + j * 16 + l15] = (bf16)S[kc][j][r];
    __syncthreads();                       // P visible
    __builtin_amdgcn_s_setprio(1);
#pragma unroll
    for (int ks = 0; ks < 4; ++ks) {
      bf16x8 pa = *(const bf16x8*)(Plw + l15 * VLP + ks * 32 + q8);
#pragma unroll
      for (int n = 0; n < 5; ++n) {
        int d = n * 16 + l15;
        // global chunk (ks*4+quad) lives at LDS chunk ^(d&7)
        int chl = (ks * 4 + quad) ^ (d & 7);
        bf16x8 vb = *(const bf16x8*)(vbuf + d * 128 + chl * 8);
        O[n] = __builtin_amdgcn_mfma_f32_16x16x32_bf16(pa, vb, O[n], 0, 0, 0);
      }
    }
    __builtin_amdgcn_s_setprio(0);
  }

#pragma unroll
  for (int n = 0; n < 5; ++n)
#pragma unroll
    for (int r = 0; r < 4; ++r) {
      int row = tw + quad * 4 + r;
      int col = h * HD + n * 16 + l15;
      out[(size_t)row * D_DIM + col] = (bf16)(O[n][r] / vsum[r]);
    }
}

// ---------------------------------------------------------------------------
// K4: proj GEMM, BM=64 BN=128 BK=32, 4 waves, wave = 32x64 (MI=2, NJ=4).
// 4-slot LDS ring, counted vmcnt (issue kt+2; wait vmcnt(6) => tiles kt+1,
// kt+2 in flight, tile kt landed; ONE s_barrier/iter). 49152 B LDS =>
// 3 blocks/CU. fp32 out + bias. A-sharing XCD swizzle (lin%8 == mt%8).
// ---------------------------------------------------------------------------
__global__ __launch_bounds__(256, 2) void gemm_proj(
    const bf16* __restrict__ A, const bf16* __restrict__ W,
    const float* __restrict__ bias, float* __restrict__ out)
{
  constexpr int BM = 64, BN = 128, MI = 2, NJ = 4;
  constexpr int K = 1280, N = 1280;
  constexpr int ASLOT = BM * 32;            // 2048
  constexpr int BSLOT = BN * 32;            // 4096
  __shared__ __align__(16) bf16 smem[4 * (ASLOT + BSLOT)];
  bf16* As = smem;
  bf16* Bs = smem + 4 * ASLOT;

  int tid  = threadIdx.x;
  int wave = tid >> 6, lane = tid & 63;
  int l15 = lane & 15, quad = lane >> 4;
  int q8s = ((quad ^ ((l15 >> 1) & 3)) * 8);
  int tiles_m = 64;                         // 4096/64
  int mt = blockIdx.x % tiles_m;
  int nt = blockIdx.x / tiles_m;
  int m0 = mt * BM, n0 = nt * BN;
  int wm = (wave >> 1) * (BM / 2), wn = (wave & 1) * (BN / 2);

  int er  = tid >> 2;
  int ec8 = (((tid & 3) ^ ((tid >> 3) & 3)) * 8);
  const bf16* ga = A + (size_t)(m0 + er) * K + ec8;
  const bf16* gb = W + (size_t)(n0 + er) * K + ec8;

  auto issueN = [&](int k, int s) {        // 3 VMEM instrs per thread
    bf16* la = As + s * ASLOT + tid * 8;
    bf16* lb = Bs + s * BSLOT + tid * 8;
    gload16(ga + k, la);
    gload16(gb + k, lb);
    gload16(gb + (size_t)64 * K + k, lb + 2048);
  };

  f32x4 acc[MI][NJ];
#pragma unroll
  for (int i = 0; i < MI; ++i)
#pragma unroll
    for (int j = 0; j < NJ; ++j) acc[i][j] = (f32x4){0.f, 0.f, 0.f, 0.f};

  constexpr int NK = K / 32;               // 40
  issueN(0, 0);
  issueN(32, 1);
  for (int kt = 0; kt < NK; ++kt) {
    int p = kt & 3;
    if (kt + 2 < NK) {
      issueN((kt + 2) * 32, (kt + 2) & 3);
      WAITVM(6);                           // tile kt landed; kt+1,kt+2 fly
    } else if (kt + 1 < NK) {
      WAITVM(3);
    } else {
      WAITVM(0);
    }
    SBAR();
    bf16x8 af[MI], bfr[NJ];
#pragma unroll
    for (int i = 0; i < MI; ++i)
      af[i] = *(const bf16x8*)(As + p * ASLOT + (wm + i * 16 + l15) * 32 + q8s);
#pragma unroll
    for (int j = 0; j < NJ; ++j)
      bfr[j] = *(const bf16x8*)(Bs + p * BSLOT + (wn + j * 16 + l15) * 32 + q8s);
    __builtin_amdgcn_s_setprio(1);
#pragma unroll
    for (int i = 0; i < MI; ++i)
#pragma unroll
      for (int j = 0; j < NJ; ++j)
        acc[i][j] = __builtin_amdgcn_mfma_f32_16x16x32_bf16(af[i], bfr[j], acc[i][j], 0, 0, 0);
    __builtin_amdgcn_s_setprio(0);
  }

#pragma unroll
  for (int j = 0; j < NJ; ++j) {
    int col = n0 + wn + j * 16 + l15;
    float bv = bias[col];
#pragma unroll
    for (int i = 0; i < MI; ++i)
#pragma unroll
      for (int r = 0; r < 4; ++r) {
        int row = m0 + wm + i * 16 + quad * 4 + r;
        out[(size_t)row * N + col] = acc[i][j][r] + bv;
      }
  }
}

// ---------------------------------------------------------------------------
extern "C" void kernel_launch(void* const* d_in, const int* in_sizes, int n_in,
                              void* d_out, int out_size, void* d_ws, size_t ws_size,
                              hipStream_t stream)
{
  const float* hidden = (const float*)d_in[0];
  // d_in[1]: cu_seqlens (int32) — fixed 8x512 segments, handled structurally
  const float* rot    = (const float*)d_in[2];
  const float* qkv_w  = (const float*)d_in[3];
  const float* qkv_b  = (const float*)d_in[4];
  const float* proj_w = (const float*)d_in[5];
  const float* proj_b = (const float*)d_in[6];
  float* out = (float*)d_out;

  char* ws = (char*)d_ws;
  bf16* qkvw_bf  = (bf16*)(ws);              //  9,830,400 B [3840][1280]
  bf16* projw_bf = (bf16*)(ws +  9830400);   //  3,276,800 B [1280][1280]
  bf16* hid_bf   = (bf16*)(ws + 13107200);   // 10,485,760 B [4096][1280]
  bf16* attn     = (bf16*)(ws + 13107200);   // reuses hid_bf (dead after K1)
  bf16* Qh       = (bf16*)(ws + 23592960);   // 12,582,912 B [16][4096][96]
  bf16* Kh       = (bf16*)(ws + 36175872);   // 12,582,912 B
  bf16* Vt       = (bf16*)(ws + 48758784);   // 10,485,760 B [16][80][4096]
                                             // total 59,244,544 B

  cvt_all<<<dim3(11520), dim3(256), 0, stream>>>(
      hidden, qkv_w, proj_w, hid_bf, qkvw_bf, projw_bf);
  // K1: qkv GEMM + fused rope, 32x24 tiles of 128x160, XCD = nt%8 mapping
  gemm_qkv<<<dim3(768), dim3(256), 0, stream>>>(
      hid_bf, qkvw_bf, qkv_b, rot, Qh, Kh, Vt);
  // K3: block-diagonal attention, group->XCD co-located grid
  attn_kernel<<<dim3(1024), dim3(256), 0, stream>>>(Qh, Kh, Vt, attn);
  // K4: proj GEMM, 64x10 tiles of 64x128, ring + counted vmcnt
  gemm_proj<<<dim3(640), dim3(256), 0, stream>>>(
      attn, projw_bf, proj_b, out);
}

// Round 8
// 201.440 us; speedup vs baseline: 1.0908x; 1.0156x over previous
//
#include <hip/hip_runtime.h>
#include <hip/hip_bf16.h>

// ---------------------------------------------------------------------------
// Qwen2VL SDPA attention block, MI355X/gfx950. fp32 in/out, bf16 MFMA inside.
// T=4096, D=1280, H=16, HD=80, 8 segments of 512 (block-diagonal attention).
// Pipeline: [C]  convert hidden/qkv_w/proj_w fp32->bf16 (one fused kernel)
//           [K1] gemm_qkv: 128x160 tile, asymmetric ring (A 3-slot, B 2-slot)
//                counted vmcnt, 45056 B LDS = 3 blocks/CU; FUSED ROPE
//                epilogue -> Qh/Kh [h][t][96], V -> Vt[h][d][t]  (59.4 us)
//           [K3] attention: K/V DMA-staged double buffers, exact softmax;
//                P slab is wave-private -> NO barrier between P-write/P-read
//           [K4] gemm_proj: 64x160 tile (MI=2,NJ=5), 4-slot ring, counted
//                vmcnt, 512 blocks = exactly 2/CU balanced
// Ledger: R1 swizzle (conflicts->0, -4%); R2 XCD map (FETCH at floor, flat);
//  R3 counted-vmcnt+128-reg cap -> spill; R4 ring@2/CU -> K1 80us; R5 K3
//  L2-direct +32us (reverted); R6 recompose flat; R7 asym ring 62->59.4
//  (latency model disproven: MfmaUtil/VALUBusy imply ~3x wall/active stretch
//  from barrier stalls at ANY cover depth -> m97-structure ceiling).
// R8: counters imply K4 ~50us (8-MFMA/iter tile, 2.5/CU imbalanced grid) and
//  K3 has 4 removable barriers (P is wave-private). Fix both; K1 untouched.
// ---------------------------------------------------------------------------

#define T_DIM 4096
#define D_DIM 1280
#define NH    16
#define HD    80
#define HDP   96      // head dim padded to 3x32 for K=32 MFMA steps
#define SEG   512
#define VLP   136     // P LDS row stride (pad off pow2)
#define RLS   80      // rope-epilogue LDS row stride

typedef __bf16 bf16;
typedef bf16  bf16x4 __attribute__((ext_vector_type(4)));
typedef bf16  bf16x8 __attribute__((ext_vector_type(8)));
typedef float f32x4  __attribute__((ext_vector_type(4)));

#define WAITVM(n) asm volatile("s_waitcnt vmcnt(" #n ")" ::: "memory")
#define SBAR()    asm volatile("s_barrier" ::: "memory")

__device__ __forceinline__ void gload16(const bf16* g, bf16* l) {
  __builtin_amdgcn_global_load_lds(
      (const __attribute__((address_space(1))) void*)g,
      (__attribute__((address_space(3))) void*)l, 16, 0, 0);
}

// ---------------------------------------------------------------------------
// Fused fp32->bf16 convert of hidden (1310720 f4), qkv_w (1228800 f4),
// proj_w (409600 f4). Grid covers 2949120 float4 groups.
// ---------------------------------------------------------------------------
__global__ __launch_bounds__(256) void cvt_all(
    const float* __restrict__ hid, const float* __restrict__ qw,
    const float* __restrict__ pw, bf16* __restrict__ hb,
    bf16* __restrict__ qwb, bf16* __restrict__ pwb)
{
  int i = blockIdx.x * 256 + threadIdx.x;
  const float* src; bf16* dst; int off;
  if (i < 1310720)      { src = hid; dst = hb;  off = i; }
  else if (i < 2539520) { src = qw;  dst = qwb; off = i - 1310720; }
  else                  { src = pw;  dst = pwb; off = i - 2539520; }
  float4 v = ((const float4*)src)[off];
  ((bf16x4*)dst)[off] = (bf16x4){(bf16)v.x, (bf16)v.y, (bf16)v.z, (bf16)v.w};
}

// ---------------------------------------------------------------------------
// K1: qkv GEMM, BM=128 BN=160 BK=32, 4 waves (2x2), wave = 64x80 (one head
// per wave-half). Asymmetric staging ring: A 3 slots / B 2 slots via
// global_load_lds; per iter: WAITVM(2) -> SBAR -> issueB(kt+1) ->
// issueA(kt+2) -> frag reads -> MFMA. In-order vmcnt retirement + B-first
// stream order => vmcnt<=2 proves A(kt),B(kt) landed (suffix = A(kt+1)).
// LDS rows 32 bf16 = 4 chunks of 16 B, chunk c of row r holds logical chunk
// c ^ ((r>>1)&3) (pre-swizzled global source, deswizzled frag read).
// Grid: mt=lin/24, nt=lin%24 (24%8==0 => XCD=nt%8, W-tile L2-resident).
// Epilogue: Q/K -> wave LDS -> rope -> [h][t][96] chunks XOR-swizzled by
// ((t>>1)&3); V -> Vt[h][d][T] bf16x4 scatter.   (R7 form, unchanged)
// ---------------------------------------------------------------------------
__global__ __launch_bounds__(256, 3) void gemm_qkv(
    const bf16* __restrict__ A, const bf16* __restrict__ W,
    const float* __restrict__ bias, const float* __restrict__ rot,
    bf16* __restrict__ Qh, bf16* __restrict__ Kh, bf16* __restrict__ Vt)
{
  constexpr int BM = 128, BN = 160, MI = 4, NJ = 5;
  constexpr int K = 1280;
  constexpr int ASLOT = BM * 32;                  // 4096 elems / slot
  constexpr int BSLOT = BN * 32;                  // 5120 elems / slot
  constexpr int STAGE = 3 * ASLOT + 2 * BSLOT;    // 22528 elems = 45056 B
  constexpr int EPIB  = 4 * 64 * RLS;             // 20480 elems
  constexpr int LDSZ  = (STAGE > EPIB ? STAGE : EPIB);
  __shared__ __align__(16) bf16 smem[LDSZ];
  bf16* As = smem;                                // 3 slots
  bf16* Bs = smem + 3 * ASLOT;                    // 2 slots

  int tid  = threadIdx.x;
  int wave = tid >> 6, lane = tid & 63;
  int l15 = lane & 15, quad = lane >> 4;
  int q8s = ((quad ^ ((l15 >> 1) & 3)) * 8);      // frag-read deswizzle
  int mt = blockIdx.x / 24;
  int nt = blockIdx.x % 24;
  int m0 = mt * BM, n0 = nt * BN;
  int wm = (wave >> 1) * (BM / 2), wn = (wave & 1) * (BN / 2);

  int er  = tid >> 2;
  int ec8 = (((tid & 3) ^ ((tid >> 3) & 3)) * 8); // source pre-swizzle
  const bf16* ga = A + (size_t)(m0 + er) * K + ec8;
  const bf16* gb = W + (size_t)(n0 + er) * K + ec8;

  auto issueA = [&](int k, int s) {
    bf16* la = As + s * ASLOT + tid * 8;
    gload16(ga + k, la);
    gload16(ga + (size_t)64 * K + k, la + 2048);
  };
  auto issueB = [&](int k, int s) {
    bf16* lb = Bs + s * BSLOT + tid * 8;
    gload16(gb + k, lb);
    gload16(gb + (size_t)64 * K + k, lb + 2048);
    if (tid < 128) gload16(gb + (size_t)128 * K + k, lb + 4096);
  };

  f32x4 acc[MI][NJ];
#pragma unroll
  for (int i = 0; i < MI; ++i)
#pragma unroll
    for (int j = 0; j < NJ; ++j) acc[i][j] = (f32x4){0.f, 0.f, 0.f, 0.f};

  constexpr int NK = K / 32;                      // 40
  issueA(0, 0);
  issueB(0, 0);
  issueA(32, 1);
  for (int kt = 0; kt < NK; ++kt) {
    if (kt + 1 < NK) { WAITVM(2); } else { WAITVM(0); }
    SBAR();                                       // tile kt visible block-wide
    if (kt + 1 < NK) issueB((kt + 1) * 32, (kt + 1) & 1);
    if (kt + 2 < NK) issueA((kt + 2) * 32, (kt + 2) % 3);
    bf16x8 af[MI], bfr[NJ];
    const bf16* ap = As + (kt % 3) * ASLOT;
    const bf16* bp = Bs + (kt & 1) * BSLOT;
#pragma unroll
    for (int i = 0; i < MI; ++i)
      af[i] = *(const bf16x8*)(ap + (wm + i * 16 + l15) * 32 + q8s);
#pragma unroll
    for (int j = 0; j < NJ; ++j)
      bfr[j] = *(const bf16x8*)(bp + (wn + j * 16 + l15) * 32 + q8s);
#pragma unroll
    for (int i = 0; i < MI; ++i)
#pragma unroll
      for (int j = 0; j < NJ; ++j)
        acc[i][j] = __builtin_amdgcn_mfma_f32_16x16x32_bf16(af[i], bfr[j], acc[i][j], 0, 0, 0);
  }

  int c0  = n0 + wn;                 // wave's first col = head base
  int sel = c0 / D_DIM;              // 0=Q, 1=K, 2=V (block-uniform)
  if (sel < 2) {
    // ---- fused rope epilogue ----
    __syncthreads();                 // all frag reads done; reuse smem
    bf16* Lw = smem + wave * (64 * RLS);
    int cc0 = c0 - sel * D_DIM;
    int h   = cc0 / HD;
#pragma unroll
    for (int j = 0; j < NJ; ++j) {
      float bv = bias[c0 + j * 16 + l15];
#pragma unroll
      for (int i = 0; i < MI; ++i)
#pragma unroll
        for (int r = 0; r < 4; ++r)
          Lw[(i * 16 + quad * 4 + r) * RLS + j * 16 + l15] = (bf16)(acc[i][j][r] + bv);
    }
    __syncthreads();
    int t = m0 + wm + lane;          // lane = local row
    bf16x4 x[20];
#pragma unroll
    for (int a = 0; a < 20; ++a)
      x[a] = *(const bf16x4*)(Lw + lane * RLS + a * 4);
    const float* fp = rot + t * 40;
    float fr[40];
#pragma unroll
    for (int a = 0; a < 10; ++a) {
      float4 f4 = *(const float4*)(fp + a * 4);
      fr[a * 4] = f4.x; fr[a * 4 + 1] = f4.y; fr[a * 4 + 2] = f4.z; fr[a * 4 + 3] = f4.w;
    }
    const float sc = (sel == 0) ? 0.11180339887498949f : 1.0f;
    bf16* dst = ((sel == 0) ? Qh : Kh) + ((size_t)h * T_DIM + t) * HDP;
    int ksw = (t >> 1) & 3;          // row chunk swizzle
#pragma unroll
    for (int g = 0; g < 5; ++g) {
      bf16x8 c1, c2;
#pragma unroll
      for (int bb = 0; bb < 8; ++bb) {
        int a = g * 2 + (bb >> 2), b = bb & 3;
        float cs, sn;
        __sincosf(fr[a * 4 + b], &sn, &cs);
        cs *= sc; sn *= sc;
        float xa = (float)x[a][b], xb = (float)x[a + 10][b];
        c1[bb] = (bf16)(xa * cs - xb * sn);
        c2[bb] = (bf16)(xb * cs + xa * sn);
      }
      *(bf16x8*)(dst + (g ^ ksw) * 8)       = c1;
      *(bf16x8*)(dst + ((g + 5) ^ ksw) * 8) = c2;
    }
    bf16x8 z = {};
    *(bf16x8*)(dst + (10 ^ ksw) * 8) = z;
    *(bf16x8*)(dst + (11 ^ ksw) * 8) = z;
  } else {
    // ---- V scatter (transposed, t-major) ----
#pragma unroll
    for (int j = 0; j < NJ; ++j) {
      int c = c0 + j * 16 + l15;
      float bv = bias[c];
      int cc = c - 2 * D_DIM;
      int h = cc / HD, d = cc - h * HD;
      bf16* vrow = Vt + ((size_t)h * HD + d) * T_DIM;
#pragma unroll
      for (int i = 0; i < MI; ++i) {
        int t0 = m0 + wm + i * 16 + quad * 4;
        bf16x4 pv = {(bf16)(acc[i][j][0] + bv), (bf16)(acc[i][j][1] + bv),
                     (bf16)(acc[i][j][2] + bv), (bf16)(acc[i][j][3] + bv)};
        *(bf16x4*)(vrow + t0) = pv;
      }
    }
  }
}

// ---------------------------------------------------------------------------
// K3: attention (staged form). Grid 1024; all 8 tiles of (seg,head) group g
// land on XCD g%8 => K/V L2-resident. K/V staged via global_load_lds into
// double buffers; one barrier per QK chunk; V(0) prefetch issued during the
// last QK chunk and drains behind the softmax VALU stretch. V chunks
// XOR-swizzled (chunk ^ (d&7)). Qh/Kh rows arrive chunk-swizzled by
// ((t>>1)&3) (from K1); qf/kb deswizzle. s_setprio(1) around MFMA clusters.
// R8: NO barrier between P-write and P-read — the P slab is wave-private
// (Pl + wave*16*VLP; each wave reads only its own slab) and per-wave LDS
// ops are in-order, so only the per-chunk V-drain barrier remains.
// ---------------------------------------------------------------------------
__global__ __launch_bounds__(256, 2) void attn_kernel(
    const bf16* __restrict__ Qh, const bf16* __restrict__ Kh,
    const bf16* __restrict__ Vt, bf16* __restrict__ out)
{
  // KV double buffers 2 x 24576 B (K [128][96] / V [80][128]); P 17408 B
  __shared__ __align__(16) char smem[66560];
  bf16* KV[2] = {(bf16*)smem, (bf16*)(smem + 24576)};
  bf16* Pl    = (bf16*)(smem + 49152);

  int lin  = blockIdx.x;
  int g    = lin & 127;        // (seg,head) group
  int tile = lin >> 7;         // 0..7
  int h    = g & 15;
  int seg  = g >> 4;
  int seg0 = seg * SEG;
  int t0   = seg0 + tile * 64;

  int tid  = threadIdx.x;
  int wave = tid >> 6;
  int lane = tid & 63;
  int l15 = lane & 15, quad = lane >> 4, q8 = quad * 8;
  int qs8 = ((quad ^ ((l15 >> 1) & 3)) * 8);   // Qh/Kh chunk deswizzle
  int tw = t0 + wave * 16;

  const bf16* khbase = Kh + ((size_t)h * T_DIM + seg0) * HDP;
  const bf16* vtbase = Vt + (size_t)h * HD * T_DIM + seg0;

  auto issueK = [&](int kc, bf16* buf) {
    const bf16* src = khbase + (size_t)kc * (128 * HDP);
#pragma unroll
    for (int i = 0; i < 6; ++i)
      gload16(src + (i * 256 + tid) * 8, buf + (i * 256 + tid) * 8);
  };
  auto issueV = [&](int kc, bf16* buf) {
    const bf16* src = vtbase + kc * 128;
#pragma unroll
    for (int i = 0; i < 5; ++i) {
      int idx = i * 256 + tid;            // 0..1279
      int d = idx >> 4, ch = idx & 15;
      int chg = ch ^ (d & 7);             // XOR source-chunk swizzle
      gload16(src + (size_t)d * T_DIM + chg * 8, buf + idx * 8);
    }
  };

  issueK(0, KV[0]);

  bf16x8 qf[3];
  {
    const bf16* qbase = Qh + ((size_t)h * T_DIM + tw + l15) * HDP + qs8;
#pragma unroll
    for (int kk = 0; kk < 3; ++kk) qf[kk] = *(const bf16x8*)(qbase + kk * 32);
  }

  // ---- Phase A: S = Q K^T, 4 chunks of 128 keys, 1 barrier/chunk ----
  f32x4 S[4][8];
  for (int kc = 0; kc < 4; ++kc) {
    bf16* buf = KV[kc & 1];
    __syncthreads();                       // drains DMA(kc) + prior reads
    if (kc < 3) issueK(kc + 1, KV[(kc & 1) ^ 1]);
    else        issueV(0, KV[0]);          // KV[0] free (last read chunk 2)
    __builtin_amdgcn_s_setprio(1);
#pragma unroll
    for (int j = 0; j < 8; ++j) {
      f32x4 acc = {0.f, 0.f, 0.f, 0.f};
      const bf16* kb = buf + (j * 16 + l15) * HDP + qs8;
#pragma unroll
      for (int kk = 0; kk < 3; ++kk)
        acc = __builtin_amdgcn_mfma_f32_16x16x32_bf16(qf[kk], *(const bf16x8*)(kb + kk * 32), acc, 0, 0, 0);
      S[kc][j] = acc;
    }
    __builtin_amdgcn_s_setprio(0);
  }

  // ---- Softmax (exact; scale pre-folded into Q). V(0) in flight. ----
  float vsum[4];
#pragma unroll
  for (int r = 0; r < 4; ++r) {
    float m = -1e30f;
#pragma unroll
    for (int kc = 0; kc < 4; ++kc)
#pragma unroll
      for (int j = 0; j < 8; ++j) m = fmaxf(m, S[kc][j][r]);
    for (int off = 1; off < 16; off <<= 1) m = fmaxf(m, __shfl_xor(m, off));
    float s = 0.f;
#pragma unroll
    for (int kc = 0; kc < 4; ++kc)
#pragma unroll
      for (int j = 0; j < 8; ++j) {
        float e = __expf(S[kc][j][r] - m);
        S[kc][j][r] = e;
        s += e;
      }
    for (int off = 1; off < 16; off <<= 1) s += __shfl_xor(s, off);
    vsum[r] = s;
  }

  // ---- Phase B: O = P V, 4 chunks, V prefetched one chunk ahead ----
  f32x4 O[5];
#pragma unroll
  for (int n = 0; n < 5; ++n) O[n] = (f32x4){0.f, 0.f, 0.f, 0.f};
  bf16* Plw = Pl + wave * (16 * VLP);

  for (int kc = 0; kc < 4; ++kc) {
    bf16* vbuf = KV[kc & 1];
    __syncthreads();                       // drains V(kc); prior MFMA reads done
    if (kc < 3) issueV(kc + 1, KV[(kc & 1) ^ 1]);
#pragma unroll
    for (int j = 0; j < 8; ++j)
#pragma unroll
      for (int r = 0; r < 4; ++r)
        Plw[(quad * 4 + r) * VLP + j * 16 + l15] = (bf16)S[kc][j][r];
    // no barrier: P slab is wave-private; per-wave LDS ops are in-order
    __builtin_amdgcn_s_setprio(1);
#pragma unroll
    for (int ks = 0; ks < 4; ++ks) {
      bf16x8 pa = *(const bf16x8*)(Plw + l15 * VLP + ks * 32 + q8);
#pragma unroll
      for (int n = 0; n < 5; ++n) {
        int d = n * 16 + l15;
        // global chunk (ks*4+quad) lives at LDS chunk ^(d&7)
        int chl = (ks * 4 + quad) ^ (d & 7);
        bf16x8 vb = *(const bf16x8*)(vbuf + d * 128 + chl * 8);
        O[n] = __builtin_amdgcn_mfma_f32_16x16x32_bf16(pa, vb, O[n], 0, 0, 0);
      }
    }
    __builtin_amdgcn_s_setprio(0);
  }

#pragma unroll
  for (int n = 0; n < 5; ++n)
#pragma unroll
    for (int r = 0; r < 4; ++r) {
      int row = tw + quad * 4 + r;
      int col = h * HD + n * 16 + l15;
      out[(size_t)row * D_DIM + col] = (bf16)(O[n][r] / vsum[r]);
    }
}

// ---------------------------------------------------------------------------
// K4: proj GEMM, BM=64 BN=160 BK=32, 4 waves, wave = 32x80 (MI=2, NJ=5).
// Grid 64x8 = 512 blocks = EXACTLY 2/CU, single balanced round (old 640 at
// 2.5/CU had half the CUs running 3 serial blocks). 4-slot LDS ring, counted
// vmcnt (issue kt+2; WAITVM(8) => tiles kt+1,kt+2 in flight, kt landed; one
// SBAR/iter). B staged as 192 rows (32 pad rows, clamped in-bounds sources,
// never read) => uniform 4 VMEM/thread. LDS 65536 B => 2 blocks/CU.
// fp32 out + bias. A-sharing: lin%8 == mt%8 (64%8==0) => one XCD per A-tile.
// ---------------------------------------------------------------------------
__global__ __launch_bounds__(256, 2) void gemm_proj(
    const bf16* __restrict__ A, const bf16* __restrict__ W,
    const float* __restrict__ bias, float* __restrict__ out)
{
  constexpr int BM = 64, BN = 160, MI = 2, NJ = 5;
  constexpr int K = 1280, N = 1280;
  constexpr int ASLOT = BM * 32;            // 2048 elems
  constexpr int BSLOT = 192 * 32;           // 6144 elems (160 + 32 pad rows)
  __shared__ __align__(16) bf16 smem[4 * (ASLOT + BSLOT)];   // 65536 B
  bf16* As = smem;
  bf16* Bs = smem + 4 * ASLOT;

  int tid  = threadIdx.x;
  int wave = tid >> 6, lane = tid & 63;
  int l15 = lane & 15, quad = lane >> 4;
  int q8s = ((quad ^ ((l15 >> 1) & 3)) * 8);
  int tiles_m = 64;                         // 4096/64
  int mt = blockIdx.x % tiles_m;            // lin%8 == mt%8 -> A-tile per XCD
  int nt = blockIdx.x / tiles_m;            // 0..7
  int m0 = mt * BM, n0 = nt * BN;
  int wm = (wave >> 1) * (BM / 2), wn = (wave & 1) * (BN / 2);

  int er  = tid >> 2;
  int ec8 = (((tid & 3) ^ ((tid >> 3) & 3)) * 8);
  const bf16* ga = A + (size_t)(m0 + er) * K + ec8;
  const bf16* gb = W + (size_t)(n0 + er) * K + ec8;

  auto issueN = [&](int k, int s) {        // uniform 4 VMEM instrs/thread
    bf16* la = As + s * ASLOT + tid * 8;
    bf16* lb = Bs + s * BSLOT + tid * 8;
    gload16(ga + k, la);                   // A rows 0..63
    gload16(gb + k, lb);                   // B rows 0..63
    gload16(gb + (size_t)64 * K + k, lb + 2048);   // B rows 64..127
    // B rows 128..191: rows >=160 are pad; clamp source in-bounds (row-64),
    // dest lands in the never-read pad region. Count stays uniform.
    size_t o3 = (tid < 128) ? (size_t)128 * K : (size_t)64 * K;
    gload16(gb + o3 + k, lb + 4096);
  };

  f32x4 acc[MI][NJ];
#pragma unroll
  for (int i = 0; i < MI; ++i)
#pragma unroll
    for (int j = 0; j < NJ; ++j) acc[i][j] = (f32x4){0.f, 0.f, 0.f, 0.f};

  constexpr int NK = K / 32;               // 40
  issueN(0, 0);
  issueN(32, 1);
  for (int kt = 0; kt < NK; ++kt) {
    int p = kt & 3;
    if (kt + 2 < NK) {
      issueN((kt + 2) * 32, (kt + 2) & 3);
      WAITVM(8);                           // tile kt landed; kt+1,kt+2 fly
    } else if (kt + 1 < NK) {
      WAITVM(4);
    } else {
      WAITVM(0);
    }
    SBAR();
    bf16x8 af[MI], bfr[NJ];
#pragma unroll
    for (int i = 0; i < MI; ++i)
      af[i] = *(const bf16x8*)(As + p * ASLOT + (wm + i * 16 + l15) * 32 + q8s);
#pragma unroll
    for (int j = 0; j < NJ; ++j)
      bfr[j] = *(const bf16x8*)(Bs + p * BSLOT + (wn + j * 16 + l15) * 32 + q8s);
    __builtin_amdgcn_s_setprio(1);
#pragma unroll
    for (int i = 0; i < MI; ++i)
#pragma unroll
      for (int j = 0; j < NJ; ++j)
        acc[i][j] = __builtin_amdgcn_mfma_f32_16x16x32_bf16(af[i], bfr[j], acc[i][j], 0, 0, 0);
    __builtin_amdgcn_s_setprio(0);
  }

#pragma unroll
  for (int j = 0; j < NJ; ++j) {
    int col = n0 + wn + j * 16 + l15;
    float bv = bias[col];
#pragma unroll
    for (int i = 0; i < MI; ++i)
#pragma unroll
      for (int r = 0; r < 4; ++r) {
        int row = m0 + wm + i * 16 + quad * 4 + r;
        out[(size_t)row * N + col] = acc[i][j][r] + bv;
      }
  }
}

// ---------------------------------------------------------------------------
extern "C" void kernel_launch(void* const* d_in, const int* in_sizes, int n_in,
                              void* d_out, int out_size, void* d_ws, size_t ws_size,
                              hipStream_t stream)
{
  const float* hidden = (const float*)d_in[0];
  // d_in[1]: cu_seqlens (int32) — fixed 8x512 segments, handled structurally
  const float* rot    = (const float*)d_in[2];
  const float* qkv_w  = (const float*)d_in[3];
  const float* qkv_b  = (const float*)d_in[4];
  const float* proj_w = (const float*)d_in[5];
  const float* proj_b = (const float*)d_in[6];
  float* out = (float*)d_out;

  char* ws = (char*)d_ws;
  bf16* qkvw_bf  = (bf16*)(ws);              //  9,830,400 B [3840][1280]
  bf16* projw_bf = (bf16*)(ws +  9830400);   //  3,276,800 B [1280][1280]
  bf16* hid_bf   = (bf16*)(ws + 13107200);   // 10,485,760 B [4096][1280]
  bf16* attn     = (bf16*)(ws + 13107200);   // reuses hid_bf (dead after K1)
  bf16* Qh       = (bf16*)(ws + 23592960);   // 12,582,912 B [16][4096][96]
  bf16* Kh       = (bf16*)(ws + 36175872);   // 12,582,912 B
  bf16* Vt       = (bf16*)(ws + 48758784);   // 10,485,760 B [16][80][4096]
                                             // total 59,244,544 B

  cvt_all<<<dim3(11520), dim3(256), 0, stream>>>(
      hidden, qkv_w, proj_w, hid_bf, qkvw_bf, projw_bf);
  // K1: qkv GEMM + fused rope, 32x24 tiles of 128x160, XCD = nt%8 mapping
  gemm_qkv<<<dim3(768), dim3(256), 0, stream>>>(
      hid_bf, qkvw_bf, qkv_b, rot, Qh, Kh, Vt);
  // K3: block-diagonal attention, group->XCD co-located grid
  attn_kernel<<<dim3(1024), dim3(256), 0, stream>>>(Qh, Kh, Vt, attn);
  // K4: proj GEMM, 64x8 tiles of 64x160, ring + counted vmcnt, 2/CU exact
  gemm_proj<<<dim3(512), dim3(256), 0, stream>>>(
      attn, projw_bf, proj_b, out);
}

// Round 9
// 200.396 us; speedup vs baseline: 1.0965x; 1.0052x over previous
//
#include <hip/hip_runtime.h>
#include <hip/hip_bf16.h>

// ---------------------------------------------------------------------------
// Qwen2VL SDPA attention block, MI355X/gfx950. fp32 in/out, bf16 MFMA inside.
// T=4096, D=1280, H=16, HD=80, 8 segments of 512 (block-diagonal attention).
// Pipeline: [C]  convert hidden/qkv_w/proj_w fp32->bf16 (one fused kernel)
//           [K1] gemm_qkv: 128x160 tile, asymmetric ring (A 3-slot, B 2-slot)
//                counted vmcnt, 45056 B LDS = 3 blocks/CU; FUSED ROPE
//                epilogue -> Qh/Kh [h][t][96], V -> Vt[h][d][t]  (59.4 us)
//           [K3] attention: K/V DMA-staged double buffers, exact softmax;
//                P double-buffered (VLP=128 + XOR chunk swizzle) with
//                P-write(kc+1) HOISTED to overlap the V(kc) DMA drain
//           [K4] gemm_proj: 64x160 tile (MI=2,NJ=5), 4-slot ring, counted
//                vmcnt, 512 blocks = exactly 2/CU balanced
// Ledger: R1 swizzle (conflicts->0, -4%); R2 XCD map (FETCH at floor, flat);
//  R3 counted-vmcnt+128-reg cap -> spill; R4 ring@2/CU -> K1 80us; R5 K3
//  L2-direct +32us (reverted); R6 recompose flat (cross-round attribution
//  retired); R7 asym ring 62->59.4 (m97-structure ceiling reached for K1);
//  R8 K4 dense tile + balanced 512 grid + K3 barrier removal: -3.2us.
// R9: K3's P path (128 scalar ds_writes/wave) sits between the V barrier
//  and the PV MFMAs = critical path. P is wave-private and depends only on
//  softmax => double-buffer P (2x16x128 per wave, XOR swizzle
//  (key>>3)^(row&7): reads conflict-free, writes ~4-way but hidden) and
//  hoist pwrite(kc+1) to overlap V(kc) drain. LDS 81920 = exactly 2/CU.
// ---------------------------------------------------------------------------

#define T_DIM 4096
#define D_DIM 1280
#define NH    16
#define HD    80
#define HDP   96      // head dim padded to 3x32 for K=32 MFMA steps
#define SEG   512
#define RLS   80      // rope-epilogue LDS row stride

typedef __bf16 bf16;
typedef bf16  bf16x4 __attribute__((ext_vector_type(4)));
typedef bf16  bf16x8 __attribute__((ext_vector_type(8)));
typedef float f32x4  __attribute__((ext_vector_type(4)));

#define WAITVM(n) asm volatile("s_waitcnt vmcnt(" #n ")" ::: "memory")
#define SBAR()    asm volatile("s_barrier" ::: "memory")

__device__ __forceinline__ void gload16(const bf16* g, bf16* l) {
  __builtin_amdgcn_global_load_lds(
      (const __attribute__((address_space(1))) void*)g,
      (__attribute__((address_space(3))) void*)l, 16, 0, 0);
}

// ---------------------------------------------------------------------------
// Fused fp32->bf16 convert of hidden (1310720 f4), qkv_w (1228800 f4),
// proj_w (409600 f4). Grid covers 2949120 float4 groups.
// ---------------------------------------------------------------------------
__global__ __launch_bounds__(256) void cvt_all(
    const float* __restrict__ hid, const float* __restrict__ qw,
    const float* __restrict__ pw, bf16* __restrict__ hb,
    bf16* __restrict__ qwb, bf16* __restrict__ pwb)
{
  int i = blockIdx.x * 256 + threadIdx.x;
  const float* src; bf16* dst; int off;
  if (i < 1310720)      { src = hid; dst = hb;  off = i; }
  else if (i < 2539520) { src = qw;  dst = qwb; off = i - 1310720; }
  else                  { src = pw;  dst = pwb; off = i - 2539520; }
  float4 v = ((const float4*)src)[off];
  ((bf16x4*)dst)[off] = (bf16x4){(bf16)v.x, (bf16)v.y, (bf16)v.z, (bf16)v.w};
}

// ---------------------------------------------------------------------------
// K1: qkv GEMM, BM=128 BN=160 BK=32, 4 waves (2x2), wave = 64x80 (one head
// per wave-half). Asymmetric staging ring: A 3 slots / B 2 slots via
// global_load_lds; per iter: WAITVM(2) -> SBAR -> issueB(kt+1) ->
// issueA(kt+2) -> frag reads -> MFMA. In-order vmcnt retirement + B-first
// stream order => vmcnt<=2 proves A(kt),B(kt) landed (suffix = A(kt+1)).
// LDS rows 32 bf16 = 4 chunks of 16 B, chunk c of row r holds logical chunk
// c ^ ((r>>1)&3) (pre-swizzled global source, deswizzled frag read).
// Grid: mt=lin/24, nt=lin%24 (24%8==0 => XCD=nt%8, W-tile L2-resident).
// Epilogue: Q/K -> wave LDS -> rope -> [h][t][96] chunks XOR-swizzled by
// ((t>>1)&3); V -> Vt[h][d][T] bf16x4 scatter.   (R7 form, unchanged)
// ---------------------------------------------------------------------------
__global__ __launch_bounds__(256, 3) void gemm_qkv(
    const bf16* __restrict__ A, const bf16* __restrict__ W,
    const float* __restrict__ bias, const float* __restrict__ rot,
    bf16* __restrict__ Qh, bf16* __restrict__ Kh, bf16* __restrict__ Vt)
{
  constexpr int BM = 128, BN = 160, MI = 4, NJ = 5;
  constexpr int K = 1280;
  constexpr int ASLOT = BM * 32;                  // 4096 elems / slot
  constexpr int BSLOT = BN * 32;                  // 5120 elems / slot
  constexpr int STAGE = 3 * ASLOT + 2 * BSLOT;    // 22528 elems = 45056 B
  constexpr int EPIB  = 4 * 64 * RLS;             // 20480 elems
  constexpr int LDSZ  = (STAGE > EPIB ? STAGE : EPIB);
  __shared__ __align__(16) bf16 smem[LDSZ];
  bf16* As = smem;                                // 3 slots
  bf16* Bs = smem + 3 * ASLOT;                    // 2 slots

  int tid  = threadIdx.x;
  int wave = tid >> 6, lane = tid & 63;
  int l15 = lane & 15, quad = lane >> 4;
  int q8s = ((quad ^ ((l15 >> 1) & 3)) * 8);      // frag-read deswizzle
  int mt = blockIdx.x / 24;
  int nt = blockIdx.x % 24;
  int m0 = mt * BM, n0 = nt * BN;
  int wm = (wave >> 1) * (BM / 2), wn = (wave & 1) * (BN / 2);

  int er  = tid >> 2;
  int ec8 = (((tid & 3) ^ ((tid >> 3) & 3)) * 8); // source pre-swizzle
  const bf16* ga = A + (size_t)(m0 + er) * K + ec8;
  const bf16* gb = W + (size_t)(n0 + er) * K + ec8;

  auto issueA = [&](int k, int s) {
    bf16* la = As + s * ASLOT + tid * 8;
    gload16(ga + k, la);
    gload16(ga + (size_t)64 * K + k, la + 2048);
  };
  auto issueB = [&](int k, int s) {
    bf16* lb = Bs + s * BSLOT + tid * 8;
    gload16(gb + k, lb);
    gload16(gb + (size_t)64 * K + k, lb + 2048);
    if (tid < 128) gload16(gb + (size_t)128 * K + k, lb + 4096);
  };

  f32x4 acc[MI][NJ];
#pragma unroll
  for (int i = 0; i < MI; ++i)
#pragma unroll
    for (int j = 0; j < NJ; ++j) acc[i][j] = (f32x4){0.f, 0.f, 0.f, 0.f};

  constexpr int NK = K / 32;                      // 40
  issueA(0, 0);
  issueB(0, 0);
  issueA(32, 1);
  for (int kt = 0; kt < NK; ++kt) {
    if (kt + 1 < NK) { WAITVM(2); } else { WAITVM(0); }
    SBAR();                                       // tile kt visible block-wide
    if (kt + 1 < NK) issueB((kt + 1) * 32, (kt + 1) & 1);
    if (kt + 2 < NK) issueA((kt + 2) * 32, (kt + 2) % 3);
    bf16x8 af[MI], bfr[NJ];
    const bf16* ap = As + (kt % 3) * ASLOT;
    const bf16* bp = Bs + (kt & 1) * BSLOT;
#pragma unroll
    for (int i = 0; i < MI; ++i)
      af[i] = *(const bf16x8*)(ap + (wm + i * 16 + l15) * 32 + q8s);
#pragma unroll
    for (int j = 0; j < NJ; ++j)
      bfr[j] = *(const bf16x8*)(bp + (wn + j * 16 + l15) * 32 + q8s);
#pragma unroll
    for (int i = 0; i < MI; ++i)
#pragma unroll
      for (int j = 0; j < NJ; ++j)
        acc[i][j] = __builtin_amdgcn_mfma_f32_16x16x32_bf16(af[i], bfr[j], acc[i][j], 0, 0, 0);
  }

  int c0  = n0 + wn;                 // wave's first col = head base
  int sel = c0 / D_DIM;              // 0=Q, 1=K, 2=V (block-uniform)
  if (sel < 2) {
    // ---- fused rope epilogue ----
    __syncthreads();                 // all frag reads done; reuse smem
    bf16* Lw = smem + wave * (64 * RLS);
    int cc0 = c0 - sel * D_DIM;
    int h   = cc0 / HD;
#pragma unroll
    for (int j = 0; j < NJ; ++j) {
      float bv = bias[c0 + j * 16 + l15];
#pragma unroll
      for (int i = 0; i < MI; ++i)
#pragma unroll
        for (int r = 0; r < 4; ++r)
          Lw[(i * 16 + quad * 4 + r) * RLS + j * 16 + l15] = (bf16)(acc[i][j][r] + bv);
    }
    __syncthreads();
    int t = m0 + wm + lane;          // lane = local row
    bf16x4 x[20];
#pragma unroll
    for (int a = 0; a < 20; ++a)
      x[a] = *(const bf16x4*)(Lw + lane * RLS + a * 4);
    const float* fp = rot + t * 40;
    float fr[40];
#pragma unroll
    for (int a = 0; a < 10; ++a) {
      float4 f4 = *(const float4*)(fp + a * 4);
      fr[a * 4] = f4.x; fr[a * 4 + 1] = f4.y; fr[a * 4 + 2] = f4.z; fr[a * 4 + 3] = f4.w;
    }
    const float sc = (sel == 0) ? 0.11180339887498949f : 1.0f;
    bf16* dst = ((sel == 0) ? Qh : Kh) + ((size_t)h * T_DIM + t) * HDP;
    int ksw = (t >> 1) & 3;          // row chunk swizzle
#pragma unroll
    for (int g = 0; g < 5; ++g) {
      bf16x8 c1, c2;
#pragma unroll
      for (int bb = 0; bb < 8; ++bb) {
        int a = g * 2 + (bb >> 2), b = bb & 3;
        float cs, sn;
        __sincosf(fr[a * 4 + b], &sn, &cs);
        cs *= sc; sn *= sc;
        float xa = (float)x[a][b], xb = (float)x[a + 10][b];
        c1[bb] = (bf16)(xa * cs - xb * sn);
        c2[bb] = (bf16)(xb * cs + xa * sn);
      }
      *(bf16x8*)(dst + (g ^ ksw) * 8)       = c1;
      *(bf16x8*)(dst + ((g + 5) ^ ksw) * 8) = c2;
    }
    bf16x8 z = {};
    *(bf16x8*)(dst + (10 ^ ksw) * 8) = z;
    *(bf16x8*)(dst + (11 ^ ksw) * 8) = z;
  } else {
    // ---- V scatter (transposed, t-major) ----
#pragma unroll
    for (int j = 0; j < NJ; ++j) {
      int c = c0 + j * 16 + l15;
      float bv = bias[c];
      int cc = c - 2 * D_DIM;
      int h = cc / HD, d = cc - h * HD;
      bf16* vrow = Vt + ((size_t)h * HD + d) * T_DIM;
#pragma unroll
      for (int i = 0; i < MI; ++i) {
        int t0 = m0 + wm + i * 16 + quad * 4;
        bf16x4 pv = {(bf16)(acc[i][j][0] + bv), (bf16)(acc[i][j][1] + bv),
                     (bf16)(acc[i][j][2] + bv), (bf16)(acc[i][j][3] + bv)};
        *(bf16x4*)(vrow + t0) = pv;
      }
    }
  }
}

// ---------------------------------------------------------------------------
// K3: attention. Grid 1024; all 8 tiles of (seg,head) group g land on XCD
// g%8 => K/V L2-resident. K/V staged via global_load_lds into double
// buffers; one barrier per QK chunk; V(0) prefetch issued during the last
// QK chunk and drains behind the softmax VALU stretch. V chunks
// XOR-swizzled (chunk ^ (d&7)). Qh/Kh rows arrive chunk-swizzled by
// ((t>>1)&3) (from K1); qf/kb deswizzle. s_setprio(1) around MFMA clusters.
// R9: P double-buffered per wave (2 x [16][128] bf16, XOR chunk swizzle
// (key>>3)^(row&7): b128 reads conflict-free, scalar writes ~4-way but
// hidden). pwrite(kc+1) hoisted between issueV(kc+1) and the PV MFMAs of
// chunk kc => the 128 scalar LDS writes overlap the V DMA drain instead of
// sitting on the critical path. P ops are wave-private (in-order within
// wave) => no barriers needed on P. LDS 81920 B = exactly 2 blocks/CU.
// ---------------------------------------------------------------------------
__global__ __launch_bounds__(256, 2) void attn_kernel(
    const bf16* __restrict__ Qh, const bf16* __restrict__ Kh,
    const bf16* __restrict__ Vt, bf16* __restrict__ out)
{
  // KV double buffers 2 x 24576 B (K [128][96] / V [80][128]);
  // P 4 waves x 2 slabs x [16][128] bf16 = 32768 B  => 81920 B total
  __shared__ __align__(16) char smem[81920];
  bf16* KV[2] = {(bf16*)smem, (bf16*)(smem + 24576)};
  bf16* Pl    = (bf16*)(smem + 49152);

  int lin  = blockIdx.x;
  int g    = lin & 127;        // (seg,head) group
  int tile = lin >> 7;         // 0..7
  int h    = g & 15;
  int seg  = g >> 4;
  int seg0 = seg * SEG;
  int t0   = seg0 + tile * 64;

  int tid  = threadIdx.x;
  int wave = tid >> 6;
  int lane = tid & 63;
  int l15 = lane & 15, quad = lane >> 4;
  int qs8 = ((quad ^ ((l15 >> 1) & 3)) * 8);   // Qh/Kh chunk deswizzle
  int tw = t0 + wave * 16;

  const bf16* khbase = Kh + ((size_t)h * T_DIM + seg0) * HDP;
  const bf16* vtbase = Vt + (size_t)h * HD * T_DIM + seg0;

  auto issueK = [&](int kc, bf16* buf) {
    const bf16* src = khbase + (size_t)kc * (128 * HDP);
#pragma unroll
    for (int i = 0; i < 6; ++i)
      gload16(src + (i * 256 + tid) * 8, buf + (i * 256 + tid) * 8);
  };
  auto issueV = [&](int kc, bf16* buf) {
    const bf16* src = vtbase + kc * 128;
#pragma unroll
    for (int i = 0; i < 5; ++i) {
      int idx = i * 256 + tid;            // 0..1279
      int d = idx >> 4, ch = idx & 15;
      int chg = ch ^ (d & 7);             // XOR source-chunk swizzle
      gload16(src + (size_t)d * T_DIM + chg * 8, buf + idx * 8);
    }
  };

  issueK(0, KV[0]);

  bf16x8 qf[3];
  {
    const bf16* qbase = Qh + ((size_t)h * T_DIM + tw + l15) * HDP + qs8;
#pragma unroll
    for (int kk = 0; kk < 3; ++kk) qf[kk] = *(const bf16x8*)(qbase + kk * 32);
  }

  // ---- Phase A: S = Q K^T, 4 chunks of 128 keys, 1 barrier/chunk ----
  f32x4 S[4][8];
  for (int kc = 0; kc < 4; ++kc) {
    bf16* buf = KV[kc & 1];
    __syncthreads();                       // drains DMA(kc) + prior reads
    if (kc < 3) issueK(kc + 1, KV[(kc & 1) ^ 1]);
    else        issueV(0, KV[0]);          // KV[0] free (last read chunk 2)
    __builtin_amdgcn_s_setprio(1);
#pragma unroll
    for (int j = 0; j < 8; ++j) {
      f32x4 acc = {0.f, 0.f, 0.f, 0.f};
      const bf16* kb = buf + (j * 16 + l15) * HDP + qs8;
#pragma unroll
      for (int kk = 0; kk < 3; ++kk)
        acc = __builtin_amdgcn_mfma_f32_16x16x32_bf16(qf[kk], *(const bf16x8*)(kb + kk * 32), acc, 0, 0, 0);
      S[kc][j] = acc;
    }
    __builtin_amdgcn_s_setprio(0);
  }

  // ---- Softmax (exact; scale pre-folded into Q). V(0) in flight. ----
  float vsum[4];
#pragma unroll
  for (int r = 0; r < 4; ++r) {
    float m = -1e30f;
#pragma unroll
    for (int kc = 0; kc < 4; ++kc)
#pragma unroll
      for (int j = 0; j < 8; ++j) m = fmaxf(m, S[kc][j][r]);
    for (int off = 1; off < 16; off <<= 1) m = fmaxf(m, __shfl_xor(m, off));
    float s = 0.f;
#pragma unroll
    for (int kc = 0; kc < 4; ++kc)
#pragma unroll
      for (int j = 0; j < 8; ++j) {
        float e = __expf(S[kc][j][r] - m);
        S[kc][j][r] = e;
        s += e;
      }
    for (int off = 1; off < 16; off <<= 1) s += __shfl_xor(s, off);
    vsum[r] = s;
  }

  // ---- Phase B: O = P V, 4 chunks, V prefetched one chunk ahead,
  //      P-writes double-buffered and hoisted to overlap the V DMA ----
  f32x4 O[5];
#pragma unroll
  for (int n = 0; n < 5; ++n) O[n] = (f32x4){0.f, 0.f, 0.f, 0.f};
  bf16* P0 = Pl + wave * 4096;             // two 2048-elem slabs per wave

  // P store layout: slab[row*128 + (((key>>3)^(row&7))<<3 | (key&7))]
  auto pwrite = [&](int kc, bf16* slab) {
#pragma unroll
    for (int j = 0; j < 8; ++j)
#pragma unroll
      for (int r = 0; r < 4; ++r) {
        int row = quad * 4 + r;
        int key = j * 16 + l15;
        slab[row * 128 + ((((key >> 3) ^ (row & 7)) << 3) | (key & 7))] =
            (bf16)S[kc][j][r];
      }
  };

  pwrite(0, P0);                           // overlaps V(0) DMA drain
  for (int kc = 0; kc < 4; ++kc) {
    bf16* vbuf = KV[kc & 1];
    bf16* slab = P0 + (kc & 1) * 2048;
    __syncthreads();                       // drains V(kc); prior V reads done
    if (kc < 3) {
      issueV(kc + 1, KV[(kc & 1) ^ 1]);
      pwrite(kc + 1, P0 + ((kc + 1) & 1) * 2048);   // overlaps V(kc+1) DMA
    }
    __builtin_amdgcn_s_setprio(1);
#pragma unroll
    for (int ks = 0; ks < 4; ++ks) {
      // row = l15, keys ks*32 + quad*8 + [0..8): one 16B chunk, deswizzled
      bf16x8 pa = *(const bf16x8*)(slab + l15 * 128 +
                                   (((ks * 4 + quad) ^ (l15 & 7)) << 3));
#pragma unroll
      for (int n = 0; n < 5; ++n) {
        int d = n * 16 + l15;
        // global chunk (ks*4+quad) lives at LDS chunk ^(d&7)
        int chl = (ks * 4 + quad) ^ (d & 7);
        bf16x8 vb = *(const bf16x8*)(vbuf + d * 128 + chl * 8);
        O[n] = __builtin_amdgcn_mfma_f32_16x16x32_bf16(pa, vb, O[n], 0, 0, 0);
      }
    }
    __builtin_amdgcn_s_setprio(0);
  }

#pragma unroll
  for (int n = 0; n < 5; ++n)
#pragma unroll
    for (int r = 0; r < 4; ++r) {
      int row = tw + quad * 4 + r;
      int col = h * HD + n * 16 + l15;
      out[(size_t)row * D_DIM + col] = (bf16)(O[n][r] / vsum[r]);
    }
}

// ---------------------------------------------------------------------------
// K4: proj GEMM, BM=64 BN=160 BK=32, 4 waves, wave = 32x80 (MI=2, NJ=5).
// Grid 64x8 = 512 blocks = EXACTLY 2/CU, single balanced round. 4-slot LDS
// ring, counted vmcnt (issue kt+2; WAITVM(8) => tiles kt+1,kt+2 in flight,
// kt landed; one SBAR/iter). B staged as 192 rows (32 pad rows, clamped
// in-bounds sources, never read) => uniform 4 VMEM/thread. LDS 65536 B =>
// 2 blocks/CU. fp32 out + bias. A-sharing: lin%8 == mt%8 (64%8==0).
// ---------------------------------------------------------------------------
__global__ __launch_bounds__(256, 2) void gemm_proj(
    const bf16* __restrict__ A, const bf16* __restrict__ W,
    const float* __restrict__ bias, float* __restrict__ out)
{
  constexpr int BM = 64, BN = 160, MI = 2, NJ = 5;
  constexpr int K = 1280, N = 1280;
  constexpr int ASLOT = BM * 32;            // 2048 elems
  constexpr int BSLOT = 192 * 32;           // 6144 elems (160 + 32 pad rows)
  __shared__ __align__(16) bf16 smem[4 * (ASLOT + BSLOT)];   // 65536 B
  bf16* As = smem;
  bf16* Bs = smem + 4 * ASLOT;

  int tid  = threadIdx.x;
  int wave = tid >> 6, lane = tid & 63;
  int l15 = lane & 15, quad = lane >> 4;
  int q8s = ((quad ^ ((l15 >> 1) & 3)) * 8);
  int tiles_m = 64;                         // 4096/64
  int mt = blockIdx.x % tiles_m;            // lin%8 == mt%8 -> A-tile per XCD
  int nt = blockIdx.x / tiles_m;            // 0..7
  int m0 = mt * BM, n0 = nt * BN;
  int wm = (wave >> 1) * (BM / 2), wn = (wave & 1) * (BN / 2);

  int er  = tid >> 2;
  int ec8 = (((tid & 3) ^ ((tid >> 3) & 3)) * 8);
  const bf16* ga = A + (size_t)(m0 + er) * K + ec8;
  const bf16* gb = W + (size_t)(n0 + er) * K + ec8;

  auto issueN = [&](int k, int s) {        // uniform 4 VMEM instrs/thread
    bf16* la = As + s * ASLOT + tid * 8;
    bf16* lb = Bs + s * BSLOT + tid * 8;
    gload16(ga + k, la);                   // A rows 0..63
    gload16(gb + k, lb);                   // B rows 0..63
    gload16(gb + (size_t)64 * K + k, lb + 2048);   // B rows 64..127
    // B rows 128..191: rows >=160 are pad; clamp source in-bounds (row-64),
    // dest lands in the never-read pad region. Count stays uniform.
    size_t o3 = (tid < 128) ? (size_t)128 * K : (size_t)64 * K;
    gload16(gb + o3 + k, lb + 4096);
  };

  f32x4 acc[MI][NJ];
#pragma unroll
  for (int i = 0; i < MI; ++i)
#pragma unroll
    for (int j = 0; j < NJ; ++j) acc[i][j] = (f32x4){0.f, 0.f, 0.f, 0.f};

  constexpr int NK = K / 32;               // 40
  issueN(0, 0);
  issueN(32, 1);
  for (int kt = 0; kt < NK; ++kt) {
    int p = kt & 3;
    if (kt + 2 < NK) {
      issueN((kt + 2) * 32, (kt + 2) & 3);
      WAITVM(8);                           // tile kt landed; kt+1,kt+2 fly
    } else if (kt + 1 < NK) {
      WAITVM(4);
    } else {
      WAITVM(0);
    }
    SBAR();
    bf16x8 af[MI], bfr[NJ];
#pragma unroll
    for (int i = 0; i < MI; ++i)
      af[i] = *(const bf16x8*)(As + p * ASLOT + (wm + i * 16 + l15) * 32 + q8s);
#pragma unroll
    for (int j = 0; j < NJ; ++j)
      bfr[j] = *(const bf16x8*)(Bs + p * BSLOT + (wn + j * 16 + l15) * 32 + q8s);
    __builtin_amdgcn_s_setprio(1);
#pragma unroll
    for (int i = 0; i < MI; ++i)
#pragma unroll
      for (int j = 0; j < NJ; ++j)
        acc[i][j] = __builtin_amdgcn_mfma_f32_16x16x32_bf16(af[i], bfr[j], acc[i][j], 0, 0, 0);
    __builtin_amdgcn_s_setprio(0);
  }

#pragma unroll
  for (int j = 0; j < NJ; ++j) {
    int col = n0 + wn + j * 16 + l15;
    float bv = bias[col];
#pragma unroll
    for (int i = 0; i < MI; ++i)
#pragma unroll
      for (int r = 0; r < 4; ++r) {
        int row = m0 + wm + i * 16 + quad * 4 + r;
        out[(size_t)row * N + col] = acc[i][j][r] + bv;
      }
  }
}

// ---------------------------------------------------------------------------
extern "C" void kernel_launch(void* const* d_in, const int* in_sizes, int n_in,
                              void* d_out, int out_size, void* d_ws, size_t ws_size,
                              hipStream_t stream)
{
  const float* hidden = (const float*)d_in[0];
  // d_in[1]: cu_seqlens (int32) — fixed 8x512 segments, handled structurally
  const float* rot    = (const float*)d_in[2];
  const float* qkv_w  = (const float*)d_in[3];
  const float* qkv_b  = (const float*)d_in[4];
  const float* proj_w = (const float*)d_in[5];
  const float* proj_b = (const float*)d_in[6];
  float* out = (float*)d_out;

  char* ws = (char*)d_ws;
  bf16* qkvw_bf  = (bf16*)(ws);              //  9,830,400 B [3840][1280]
  bf16* projw_bf = (bf16*)(ws +  9830400);   //  3,276,800 B [1280][1280]
  bf16* hid_bf   = (bf16*)(ws + 13107200);   // 10,485,760 B [4096][1280]
  bf16* attn     = (bf16*)(ws + 13107200);   // reuses hid_bf (dead after K1)
  bf16* Qh       = (bf16*)(ws + 23592960);   // 12,582,912 B [16][4096][96]
  bf16* Kh       = (bf16*)(ws + 36175872);   // 12,582,912 B
  bf16* Vt       = (bf16*)(ws + 48758784);   // 10,485,760 B [16][80][4096]
                                             // total 59,244,544 B

  cvt_all<<<dim3(11520), dim3(256), 0, stream>>>(
      hidden, qkv_w, proj_w, hid_bf, qkvw_bf, projw_bf);
  // K1: qkv GEMM + fused rope, 32x24 tiles of 128x160, XCD = nt%8 mapping
  gemm_qkv<<<dim3(768), dim3(256), 0, stream>>>(
      hid_bf, qkvw_bf, qkv_b, rot, Qh, Kh, Vt);
  // K3: block-diagonal attention, group->XCD co-located grid
  attn_kernel<<<dim3(1024), dim3(256), 0, stream>>>(Qh, Kh, Vt, attn);
  // K4: proj GEMM, 64x8 tiles of 64x160, ring + counted vmcnt, 2/CU exact
  gemm_proj<<<dim3(512), dim3(256), 0, stream>>>(
      attn, projw_bf, proj_b, out);
}

// Round 10
// 193.600 us; speedup vs baseline: 1.1350x; 1.0351x over previous
//
#include <hip/hip_runtime.h>
#include <hip/hip_bf16.h>

// ---------------------------------------------------------------------------
// Qwen2VL SDPA attention block, MI355X/gfx950. fp32 in/out, bf16 MFMA inside.
// T=4096, D=1280, H=16, HD=80, 8 segments of 512 (block-diagonal attention).
// Pipeline: [C]  convert hidden/qkv_w/proj_w fp32->bf16 (one fused kernel)
//           [K1] gemm_qkv: 128x160 tile, asymmetric ring (A 3-slot, B 2-slot)
//                counted vmcnt, 45056 B LDS = 3 blocks/CU; FUSED ROPE
//                epilogue -> Qh/Kh [h][t][96], V -> Vt[h][d][t]  (59.4 us)
//           [K3] attention: K/V DMA-staged double buffers, exact softmax;
//                P double-buffered, P-write hoisted under V DMA drain
//           [K4] gemm_proj: 64x160 tile, BK=64 (NK=20), dbuf, 65536 B LDS
//                = 2 blocks/CU, 512 blocks balanced
// Ledger: R1 swizzle (conflicts->0, -4%); R2 XCD map (FETCH at floor, flat);
//  R3 counted-vmcnt+128-reg cap -> spill; R4 ring@2/CU -> K1 80us; R5 K3
//  L2-direct +32us (reverted); R6 recompose flat; R7 asym ring 62->59.4
//  (K1 at m97-structure ceiling); R8 K4 density+balance + K3 barrier: -3.2;
//  R9 P-hoist: -1. Budget: K1 59 + cvt ~10 + K3+K4 ~125 (both <59).
// R10: every GEMM here is bound by (iteration count x fixed ~3700cyc
//  drain cost), not bytes/FLOPs. K4 pays K1's per-iter cost with HALF the
//  MFMA/iter over the same 40 iters. Fix: BK=64 -> NK=20, 20 MFMA/wave/iter,
//  LDS 65536 = STILL 2 blocks/CU (no occupancy loss, unlike m132/R4).
//  Rows now 8 chunks -> 3-bit XOR swizzle (source pre-swz (t&7)^((t>>3)&7),
//  read deswz (kk*4+quad)^(l15&7): 16-lane groups 2-way = free).
// ---------------------------------------------------------------------------

#define T_DIM 4096
#define D_DIM 1280
#define NH    16
#define HD    80
#define HDP   96      // head dim padded to 3x32 for K=32 MFMA steps
#define SEG   512
#define RLS   80      // rope-epilogue LDS row stride

typedef __bf16 bf16;
typedef bf16  bf16x4 __attribute__((ext_vector_type(4)));
typedef bf16  bf16x8 __attribute__((ext_vector_type(8)));
typedef float f32x4  __attribute__((ext_vector_type(4)));

#define WAITVM(n) asm volatile("s_waitcnt vmcnt(" #n ")" ::: "memory")
#define SBAR()    asm volatile("s_barrier" ::: "memory")

__device__ __forceinline__ void gload16(const bf16* g, bf16* l) {
  __builtin_amdgcn_global_load_lds(
      (const __attribute__((address_space(1))) void*)g,
      (__attribute__((address_space(3))) void*)l, 16, 0, 0);
}

// ---------------------------------------------------------------------------
// Fused fp32->bf16 convert of hidden (1310720 f4), qkv_w (1228800 f4),
// proj_w (409600 f4). Grid covers 2949120 float4 groups.
// ---------------------------------------------------------------------------
__global__ __launch_bounds__(256) void cvt_all(
    const float* __restrict__ hid, const float* __restrict__ qw,
    const float* __restrict__ pw, bf16* __restrict__ hb,
    bf16* __restrict__ qwb, bf16* __restrict__ pwb)
{
  int i = blockIdx.x * 256 + threadIdx.x;
  const float* src; bf16* dst; int off;
  if (i < 1310720)      { src = hid; dst = hb;  off = i; }
  else if (i < 2539520) { src = qw;  dst = qwb; off = i - 1310720; }
  else                  { src = pw;  dst = pwb; off = i - 2539520; }
  float4 v = ((const float4*)src)[off];
  ((bf16x4*)dst)[off] = (bf16x4){(bf16)v.x, (bf16)v.y, (bf16)v.z, (bf16)v.w};
}

// ---------------------------------------------------------------------------
// K1: qkv GEMM, BM=128 BN=160 BK=32, 4 waves (2x2), wave = 64x80 (one head
// per wave-half). Asymmetric staging ring: A 3 slots / B 2 slots via
// global_load_lds; per iter: WAITVM(2) -> SBAR -> issueB(kt+1) ->
// issueA(kt+2) -> frag reads -> MFMA. In-order vmcnt retirement + B-first
// stream order => vmcnt<=2 proves A(kt),B(kt) landed (suffix = A(kt+1)).
// LDS rows 32 bf16 = 4 chunks of 16 B, chunk c of row r holds logical chunk
// c ^ ((r>>1)&3) (pre-swizzled global source, deswizzled frag read).
// Grid: mt=lin/24, nt=lin%24 (24%8==0 => XCD=nt%8, W-tile L2-resident).
// Epilogue: Q/K -> wave LDS -> rope -> [h][t][96] chunks XOR-swizzled by
// ((t>>1)&3); V -> Vt[h][d][T] bf16x4 scatter.   (R7 form, unchanged)
// ---------------------------------------------------------------------------
__global__ __launch_bounds__(256, 3) void gemm_qkv(
    const bf16* __restrict__ A, const bf16* __restrict__ W,
    const float* __restrict__ bias, const float* __restrict__ rot,
    bf16* __restrict__ Qh, bf16* __restrict__ Kh, bf16* __restrict__ Vt)
{
  constexpr int BM = 128, BN = 160, MI = 4, NJ = 5;
  constexpr int K = 1280;
  constexpr int ASLOT = BM * 32;                  // 4096 elems / slot
  constexpr int BSLOT = BN * 32;                  // 5120 elems / slot
  constexpr int STAGE = 3 * ASLOT + 2 * BSLOT;    // 22528 elems = 45056 B
  constexpr int EPIB  = 4 * 64 * RLS;             // 20480 elems
  constexpr int LDSZ  = (STAGE > EPIB ? STAGE : EPIB);
  __shared__ __align__(16) bf16 smem[LDSZ];
  bf16* As = smem;                                // 3 slots
  bf16* Bs = smem + 3 * ASLOT;                    // 2 slots

  int tid  = threadIdx.x;
  int wave = tid >> 6, lane = tid & 63;
  int l15 = lane & 15, quad = lane >> 4;
  int q8s = ((quad ^ ((l15 >> 1) & 3)) * 8);      // frag-read deswizzle
  int mt = blockIdx.x / 24;
  int nt = blockIdx.x % 24;
  int m0 = mt * BM, n0 = nt * BN;
  int wm = (wave >> 1) * (BM / 2), wn = (wave & 1) * (BN / 2);

  int er  = tid >> 2;
  int ec8 = (((tid & 3) ^ ((tid >> 3) & 3)) * 8); // source pre-swizzle
  const bf16* ga = A + (size_t)(m0 + er) * K + ec8;
  const bf16* gb = W + (size_t)(n0 + er) * K + ec8;

  auto issueA = [&](int k, int s) {
    bf16* la = As + s * ASLOT + tid * 8;
    gload16(ga + k, la);
    gload16(ga + (size_t)64 * K + k, la + 2048);
  };
  auto issueB = [&](int k, int s) {
    bf16* lb = Bs + s * BSLOT + tid * 8;
    gload16(gb + k, lb);
    gload16(gb + (size_t)64 * K + k, lb + 2048);
    if (tid < 128) gload16(gb + (size_t)128 * K + k, lb + 4096);
  };

  f32x4 acc[MI][NJ];
#pragma unroll
  for (int i = 0; i < MI; ++i)
#pragma unroll
    for (int j = 0; j < NJ; ++j) acc[i][j] = (f32x4){0.f, 0.f, 0.f, 0.f};

  constexpr int NK = K / 32;                      // 40
  issueA(0, 0);
  issueB(0, 0);
  issueA(32, 1);
  for (int kt = 0; kt < NK; ++kt) {
    if (kt + 1 < NK) { WAITVM(2); } else { WAITVM(0); }
    SBAR();                                       // tile kt visible block-wide
    if (kt + 1 < NK) issueB((kt + 1) * 32, (kt + 1) & 1);
    if (kt + 2 < NK) issueA((kt + 2) * 32, (kt + 2) % 3);
    bf16x8 af[MI], bfr[NJ];
    const bf16* ap = As + (kt % 3) * ASLOT;
    const bf16* bp = Bs + (kt & 1) * BSLOT;
#pragma unroll
    for (int i = 0; i < MI; ++i)
      af[i] = *(const bf16x8*)(ap + (wm + i * 16 + l15) * 32 + q8s);
#pragma unroll
    for (int j = 0; j < NJ; ++j)
      bfr[j] = *(const bf16x8*)(bp + (wn + j * 16 + l15) * 32 + q8s);
#pragma unroll
    for (int i = 0; i < MI; ++i)
#pragma unroll
      for (int j = 0; j < NJ; ++j)
        acc[i][j] = __builtin_amdgcn_mfma_f32_16x16x32_bf16(af[i], bfr[j], acc[i][j], 0, 0, 0);
  }

  int c0  = n0 + wn;                 // wave's first col = head base
  int sel = c0 / D_DIM;              // 0=Q, 1=K, 2=V (block-uniform)
  if (sel < 2) {
    // ---- fused rope epilogue ----
    __syncthreads();                 // all frag reads done; reuse smem
    bf16* Lw = smem + wave * (64 * RLS);
    int cc0 = c0 - sel * D_DIM;
    int h   = cc0 / HD;
#pragma unroll
    for (int j = 0; j < NJ; ++j) {
      float bv = bias[c0 + j * 16 + l15];
#pragma unroll
      for (int i = 0; i < MI; ++i)
#pragma unroll
        for (int r = 0; r < 4; ++r)
          Lw[(i * 16 + quad * 4 + r) * RLS + j * 16 + l15] = (bf16)(acc[i][j][r] + bv);
    }
    __syncthreads();
    int t = m0 + wm + lane;          // lane = local row
    bf16x4 x[20];
#pragma unroll
    for (int a = 0; a < 20; ++a)
      x[a] = *(const bf16x4*)(Lw + lane * RLS + a * 4);
    const float* fp = rot + t * 40;
    float fr[40];
#pragma unroll
    for (int a = 0; a < 10; ++a) {
      float4 f4 = *(const float4*)(fp + a * 4);
      fr[a * 4] = f4.x; fr[a * 4 + 1] = f4.y; fr[a * 4 + 2] = f4.z; fr[a * 4 + 3] = f4.w;
    }
    const float sc = (sel == 0) ? 0.11180339887498949f : 1.0f;
    bf16* dst = ((sel == 0) ? Qh : Kh) + ((size_t)h * T_DIM + t) * HDP;
    int ksw = (t >> 1) & 3;          // row chunk swizzle
#pragma unroll
    for (int g = 0; g < 5; ++g) {
      bf16x8 c1, c2;
#pragma unroll
      for (int bb = 0; bb < 8; ++bb) {
        int a = g * 2 + (bb >> 2), b = bb & 3;
        float cs, sn;
        __sincosf(fr[a * 4 + b], &sn, &cs);
        cs *= sc; sn *= sc;
        float xa = (float)x[a][b], xb = (float)x[a + 10][b];
        c1[bb] = (bf16)(xa * cs - xb * sn);
        c2[bb] = (bf16)(xb * cs + xa * sn);
      }
      *(bf16x8*)(dst + (g ^ ksw) * 8)       = c1;
      *(bf16x8*)(dst + ((g + 5) ^ ksw) * 8) = c2;
    }
    bf16x8 z = {};
    *(bf16x8*)(dst + (10 ^ ksw) * 8) = z;
    *(bf16x8*)(dst + (11 ^ ksw) * 8) = z;
  } else {
    // ---- V scatter (transposed, t-major) ----
#pragma unroll
    for (int j = 0; j < NJ; ++j) {
      int c = c0 + j * 16 + l15;
      float bv = bias[c];
      int cc = c - 2 * D_DIM;
      int h = cc / HD, d = cc - h * HD;
      bf16* vrow = Vt + ((size_t)h * HD + d) * T_DIM;
#pragma unroll
      for (int i = 0; i < MI; ++i) {
        int t0 = m0 + wm + i * 16 + quad * 4;
        bf16x4 pv = {(bf16)(acc[i][j][0] + bv), (bf16)(acc[i][j][1] + bv),
                     (bf16)(acc[i][j][2] + bv), (bf16)(acc[i][j][3] + bv)};
        *(bf16x4*)(vrow + t0) = pv;
      }
    }
  }
}

// ---------------------------------------------------------------------------
// K3: attention. Grid 1024; all 8 tiles of (seg,head) group g land on XCD
// g%8 => K/V L2-resident. K/V staged via global_load_lds into double
// buffers; one barrier per QK chunk; V(0) prefetch issued during the last
// QK chunk and drains behind the softmax VALU stretch. V chunks
// XOR-swizzled (chunk ^ (d&7)). Qh/Kh rows arrive chunk-swizzled by
// ((t>>1)&3) (from K1); qf/kb deswizzle. s_setprio(1) around MFMA clusters.
// P double-buffered per wave (2 x [16][128] bf16, XOR chunk swizzle
// (key>>3)^(row&7)); pwrite(kc+1) hoisted to overlap the V DMA drain.
// LDS 81920 B = exactly 2 blocks/CU.   (R9 form, unchanged)
// ---------------------------------------------------------------------------
__global__ __launch_bounds__(256, 2) void attn_kernel(
    const bf16* __restrict__ Qh, const bf16* __restrict__ Kh,
    const bf16* __restrict__ Vt, bf16* __restrict__ out)
{
  // KV double buffers 2 x 24576 B (K [128][96] / V [80][128]);
  // P 4 waves x 2 slabs x [16][128] bf16 = 32768 B  => 81920 B total
  __shared__ __align__(16) char smem[81920];
  bf16* KV[2] = {(bf16*)smem, (bf16*)(smem + 24576)};
  bf16* Pl    = (bf16*)(smem + 49152);

  int lin  = blockIdx.x;
  int g    = lin & 127;        // (seg,head) group
  int tile = lin >> 7;         // 0..7
  int h    = g & 15;
  int seg  = g >> 4;
  int seg0 = seg * SEG;
  int t0   = seg0 + tile * 64;

  int tid  = threadIdx.x;
  int wave = tid >> 6;
  int lane = tid & 63;
  int l15 = lane & 15, quad = lane >> 4;
  int qs8 = ((quad ^ ((l15 >> 1) & 3)) * 8);   // Qh/Kh chunk deswizzle
  int tw = t0 + wave * 16;

  const bf16* khbase = Kh + ((size_t)h * T_DIM + seg0) * HDP;
  const bf16* vtbase = Vt + (size_t)h * HD * T_DIM + seg0;

  auto issueK = [&](int kc, bf16* buf) {
    const bf16* src = khbase + (size_t)kc * (128 * HDP);
#pragma unroll
    for (int i = 0; i < 6; ++i)
      gload16(src + (i * 256 + tid) * 8, buf + (i * 256 + tid) * 8);
  };
  auto issueV = [&](int kc, bf16* buf) {
    const bf16* src = vtbase + kc * 128;
#pragma unroll
    for (int i = 0; i < 5; ++i) {
      int idx = i * 256 + tid;            // 0..1279
      int d = idx >> 4, ch = idx & 15;
      int chg = ch ^ (d & 7);             // XOR source-chunk swizzle
      gload16(src + (size_t)d * T_DIM + chg * 8, buf + idx * 8);
    }
  };

  issueK(0, KV[0]);

  bf16x8 qf[3];
  {
    const bf16* qbase = Qh + ((size_t)h * T_DIM + tw + l15) * HDP + qs8;
#pragma unroll
    for (int kk = 0; kk < 3; ++kk) qf[kk] = *(const bf16x8*)(qbase + kk * 32);
  }

  // ---- Phase A: S = Q K^T, 4 chunks of 128 keys, 1 barrier/chunk ----
  f32x4 S[4][8];
  for (int kc = 0; kc < 4; ++kc) {
    bf16* buf = KV[kc & 1];
    __syncthreads();                       // drains DMA(kc) + prior reads
    if (kc < 3) issueK(kc + 1, KV[(kc & 1) ^ 1]);
    else        issueV(0, KV[0]);          // KV[0] free (last read chunk 2)
    __builtin_amdgcn_s_setprio(1);
#pragma unroll
    for (int j = 0; j < 8; ++j) {
      f32x4 acc = {0.f, 0.f, 0.f, 0.f};
      const bf16* kb = buf + (j * 16 + l15) * HDP + qs8;
#pragma unroll
      for (int kk = 0; kk < 3; ++kk)
        acc = __builtin_amdgcn_mfma_f32_16x16x32_bf16(qf[kk], *(const bf16x8*)(kb + kk * 32), acc, 0, 0, 0);
      S[kc][j] = acc;
    }
    __builtin_amdgcn_s_setprio(0);
  }

  // ---- Softmax (exact; scale pre-folded into Q). V(0) in flight. ----
  float vsum[4];
#pragma unroll
  for (int r = 0; r < 4; ++r) {
    float m = -1e30f;
#pragma unroll
    for (int kc = 0; kc < 4; ++kc)
#pragma unroll
      for (int j = 0; j < 8; ++j) m = fmaxf(m, S[kc][j][r]);
    for (int off = 1; off < 16; off <<= 1) m = fmaxf(m, __shfl_xor(m, off));
    float s = 0.f;
#pragma unroll
    for (int kc = 0; kc < 4; ++kc)
#pragma unroll
      for (int j = 0; j < 8; ++j) {
        float e = __expf(S[kc][j][r] - m);
        S[kc][j][r] = e;
        s += e;
      }
    for (int off = 1; off < 16; off <<= 1) s += __shfl_xor(s, off);
    vsum[r] = s;
  }

  // ---- Phase B: O = P V, 4 chunks, V prefetched one chunk ahead,
  //      P-writes double-buffered and hoisted to overlap the V DMA ----
  f32x4 O[5];
#pragma unroll
  for (int n = 0; n < 5; ++n) O[n] = (f32x4){0.f, 0.f, 0.f, 0.f};
  bf16* P0 = Pl + wave * 4096;             // two 2048-elem slabs per wave

  // P store layout: slab[row*128 + (((key>>3)^(row&7))<<3 | (key&7))]
  auto pwrite = [&](int kc, bf16* slab) {
#pragma unroll
    for (int j = 0; j < 8; ++j)
#pragma unroll
      for (int r = 0; r < 4; ++r) {
        int row = quad * 4 + r;
        int key = j * 16 + l15;
        slab[row * 128 + ((((key >> 3) ^ (row & 7)) << 3) | (key & 7))] =
            (bf16)S[kc][j][r];
      }
  };

  pwrite(0, P0);                           // overlaps V(0) DMA drain
  for (int kc = 0; kc < 4; ++kc) {
    bf16* vbuf = KV[kc & 1];
    bf16* slab = P0 + (kc & 1) * 2048;
    __syncthreads();                       // drains V(kc); prior V reads done
    if (kc < 3) {
      issueV(kc + 1, KV[(kc & 1) ^ 1]);
      pwrite(kc + 1, P0 + ((kc + 1) & 1) * 2048);   // overlaps V(kc+1) DMA
    }
    __builtin_amdgcn_s_setprio(1);
#pragma unroll
    for (int ks = 0; ks < 4; ++ks) {
      // row = l15, keys ks*32 + quad*8 + [0..8): one 16B chunk, deswizzled
      bf16x8 pa = *(const bf16x8*)(slab + l15 * 128 +
                                   (((ks * 4 + quad) ^ (l15 & 7)) << 3));
#pragma unroll
      for (int n = 0; n < 5; ++n) {
        int d = n * 16 + l15;
        // global chunk (ks*4+quad) lives at LDS chunk ^(d&7)
        int chl = (ks * 4 + quad) ^ (d & 7);
        bf16x8 vb = *(const bf16x8*)(vbuf + d * 128 + chl * 8);
        O[n] = __builtin_amdgcn_mfma_f32_16x16x32_bf16(pa, vb, O[n], 0, 0, 0);
      }
    }
    __builtin_amdgcn_s_setprio(0);
  }

#pragma unroll
  for (int n = 0; n < 5; ++n)
#pragma unroll
    for (int r = 0; r < 4; ++r) {
      int row = tw + quad * 4 + r;
      int col = h * HD + n * 16 + l15;
      out[(size_t)row * D_DIM + col] = (bf16)(O[n][r] / vsum[r]);
    }
}

// ---------------------------------------------------------------------------
// K4: proj GEMM, BM=64 BN=160 BK=64, 4 waves, wave = 32x80 (MI=2, NJ=5,
// kk=2 => 20 MFMA/wave/iter, NK=20). Grid 64x8 = 512 blocks = exactly 2/CU.
// 2-slot dbuf via global_load_lds, __syncthreads drain per iter (half the
// drains of BK=32). LDS 2x(64x64 A + 192x64 B) = 65536 B => 2 blocks/CU.
// Rows = 128 B = 8 chunks: chunk c of row r holds logical chunk c ^ (r&7)
// (staging source pre-swizzle (t&7)^((t>>3)&7), frag-read deswizzle
// (kk*4+quad)^(l15&7): per 16-lane group 8 distinct chunks x2 = 2-way free).
// B staged as 192 rows (uniform 8 VMEM/thread; pad rows 160..191 source-
// clamped to rows 96..127, never read). fp32 out + bias.
// A-sharing: lin%8 == mt%8 (64%8==0) => one XCD per A-tile.
// ---------------------------------------------------------------------------
__global__ __launch_bounds__(256, 2) void gemm_proj(
    const bf16* __restrict__ A, const bf16* __restrict__ W,
    const float* __restrict__ bias, float* __restrict__ out)
{
  constexpr int BM = 64, BN = 160, MI = 2, NJ = 5;
  constexpr int K = 1280, N = 1280, BK = 64;
  constexpr int ASLOT = BM * BK;            // 4096 elems (8 KB)
  constexpr int BSLOT = 192 * BK;           // 12288 elems (24 KB)
  __shared__ __align__(16) bf16 smem[2 * (ASLOT + BSLOT)];   // 65536 B
  bf16* As = smem;                          // 2 slots
  bf16* Bs = smem + 2 * ASLOT;              // 2 slots

  int tid  = threadIdx.x;
  int wave = tid >> 6, lane = tid & 63;
  int l15 = lane & 15, quad = lane >> 4;
  int l7  = l15 & 7;
  int tiles_m = 64;                         // 4096/64
  int mt = blockIdx.x % tiles_m;            // lin%8 == mt%8 -> A-tile per XCD
  int nt = blockIdx.x / tiles_m;            // 0..7
  int m0 = mt * BM, n0 = nt * BN;
  int wm = (wave >> 1) * (BM / 2), wn = (wave & 1) * (BN / 2);

  int er  = tid >> 3;                       // staging row 0..31
  int ec8 = (((tid & 7) ^ ((tid >> 3) & 7)) * 8);  // source chunk pre-swizzle
  const bf16* ga = A + (size_t)(m0 + er) * K + ec8;
  const bf16* gb = W + (size_t)(n0 + er) * K + ec8;

  auto issueN = [&](int k, int s) {        // uniform 8 VMEM instrs/thread
    bf16* la = As + s * ASLOT + tid * 8;
    bf16* lb = Bs + s * BSLOT + tid * 8;
    gload16(ga + k, la);                             // A rows 0..31
    gload16(ga + (size_t)32 * K + k, la + 2048);     // A rows 32..63
#pragma unroll
    for (int i = 0; i < 5; ++i)                      // B rows 0..159
      gload16(gb + (size_t)(32 * i) * K + k, lb + i * 2048);
    // B rows 160..191 are pad: clamp source to rows 96..127 (never read)
    gload16(gb + (size_t)96 * K + k, lb + 5 * 2048);
  };

  f32x4 acc[MI][NJ];
#pragma unroll
  for (int i = 0; i < MI; ++i)
#pragma unroll
    for (int j = 0; j < NJ; ++j) acc[i][j] = (f32x4){0.f, 0.f, 0.f, 0.f};

  constexpr int NK = K / BK;               // 20
  issueN(0, 0);
  for (int kt = 0; kt < NK; ++kt) {
    int p = kt & 1;
    __syncthreads();                       // drains DMA(kt) + prior frag reads
    if (kt + 1 < NK) issueN((kt + 1) * BK, p ^ 1);
    bf16x8 af[2][MI], bfr[2][NJ];
#pragma unroll
    for (int kk = 0; kk < 2; ++kk) {
      int co = ((kk * 4 + quad) ^ l7) * 8;           // deswizzled chunk
#pragma unroll
      for (int i = 0; i < MI; ++i)
        af[kk][i] = *(const bf16x8*)(As + p * ASLOT + (wm + i * 16 + l15) * 64 + co);
#pragma unroll
      for (int j = 0; j < NJ; ++j)
        bfr[kk][j] = *(const bf16x8*)(Bs + p * BSLOT + (wn + j * 16 + l15) * 64 + co);
    }
    __builtin_amdgcn_s_setprio(1);
#pragma unroll
    for (int kk = 0; kk < 2; ++kk)
#pragma unroll
      for (int i = 0; i < MI; ++i)
#pragma unroll
        for (int j = 0; j < NJ; ++j)
          acc[i][j] = __builtin_amdgcn_mfma_f32_16x16x32_bf16(af[kk][i], bfr[kk][j], acc[i][j], 0, 0, 0);
    __builtin_amdgcn_s_setprio(0);
  }

#pragma unroll
  for (int j = 0; j < NJ; ++j) {
    int col = n0 + wn + j * 16 + l15;
    float bv = bias[col];
#pragma unroll
    for (int i = 0; i < MI; ++i)
#pragma unroll
      for (int r = 0; r < 4; ++r) {
        int row = m0 + wm + i * 16 + quad * 4 + r;
        out[(size_t)row * N + col] = acc[i][j][r] + bv;
      }
  }
}

// ---------------------------------------------------------------------------
extern "C" void kernel_launch(void* const* d_in, const int* in_sizes, int n_in,
                              void* d_out, int out_size, void* d_ws, size_t ws_size,
                              hipStream_t stream)
{
  const float* hidden = (const float*)d_in[0];
  // d_in[1]: cu_seqlens (int32) — fixed 8x512 segments, handled structurally
  const float* rot    = (const float*)d_in[2];
  const float* qkv_w  = (const float*)d_in[3];
  const float* qkv_b  = (const float*)d_in[4];
  const float* proj_w = (const float*)d_in[5];
  const float* proj_b = (const float*)d_in[6];
  float* out = (float*)d_out;

  char* ws = (char*)d_ws;
  bf16* qkvw_bf  = (bf16*)(ws);              //  9,830,400 B [3840][1280]
  bf16* projw_bf = (bf16*)(ws +  9830400);   //  3,276,800 B [1280][1280]
  bf16* hid_bf   = (bf16*)(ws + 13107200);   // 10,485,760 B [4096][1280]
  bf16* attn     = (bf16*)(ws + 13107200);   // reuses hid_bf (dead after K1)
  bf16* Qh       = (bf16*)(ws + 23592960);   // 12,582,912 B [16][4096][96]
  bf16* Kh       = (bf16*)(ws + 36175872);   // 12,582,912 B
  bf16* Vt       = (bf16*)(ws + 48758784);   // 10,485,760 B [16][80][4096]
                                             // total 59,244,544 B

  cvt_all<<<dim3(11520), dim3(256), 0, stream>>>(
      hidden, qkv_w, proj_w, hid_bf, qkvw_bf, projw_bf);
  // K1: qkv GEMM + fused rope, 32x24 tiles of 128x160, XCD = nt%8 mapping
  gemm_qkv<<<dim3(768), dim3(256), 0, stream>>>(
      hid_bf, qkvw_bf, qkv_b, rot, Qh, Kh, Vt);
  // K3: block-diagonal attention, group->XCD co-located grid
  attn_kernel<<<dim3(1024), dim3(256), 0, stream>>>(Qh, Kh, Vt, attn);
  // K4: proj GEMM, 64x8 tiles of 64x160 BK=64, dbuf, 2/CU exact
  gemm_proj<<<dim3(512), dim3(256), 0, stream>>>(
      attn, projw_bf, proj_b, out);
}

// Round 11
// 191.772 us; speedup vs baseline: 1.1458x; 1.0095x over previous
//
#include <hip/hip_runtime.h>
#include <hip/hip_bf16.h>

// ---------------------------------------------------------------------------
// Qwen2VL SDPA attention block, MI355X/gfx950. fp32 in/out, bf16 MFMA inside.
// T=4096, D=1280, H=16, HD=80, 8 segments of 512 (block-diagonal attention).
// Pipeline: [C]  convert hidden/qkv_w/proj_w fp32->bf16 (one fused kernel)
//           [K1] gemm_qkv: 128x160 tile, BK=64 (NK=20), 2-phase dbuf,
//                73728 B LDS = 2 blocks/CU; FUSED ROPE epilogue ->
//                Qh/Kh [h][t][96], V -> Vt[h][d][t]
//           [K3] attention: K/V DMA-staged double buffers, exact softmax;
//                P double-buffered, P-write hoisted under V DMA drain
//           [K4] gemm_proj: 64x160 tile, BK=64 (NK=20), dbuf, 2/CU, 512
//                blocks balanced   (R10 form, VALIDATED -7us)
// Ledger: R1 swizzle (conflicts->0, -4%); R2 XCD map (FETCH at floor, flat);
//  R3 counted-vmcnt+128-reg cap -> spill; R4 ring@2/CU NK=40 -> K1 80us;
//  R5 K3 L2-direct +32us (reverted); R6 recompose flat; R7 asym ring
//  62->59.4; R8 K4 density+balance: -3.2; R9 P-hoist: -1;
//  R10 K4 BK=64: -6.8 (iteration-count x fixed-drain model VALIDATED).
// R11: same lever on K1. BK=64 -> NK=20, 40 MFMA/wave/iter; LDS 73728 ->
//  2/CU (R4 says ~4800cyc/iter there; x20 + staging ~= 46-52us < 61).
//  Rows 128 B = 8 chunks -> 3-bit XOR swizzle (K4-R10 geometry); uniform
//  9 loads/thread (A 4, B 5); accumulation order unchanged (bitwise-same).
// ---------------------------------------------------------------------------

#define T_DIM 4096
#define D_DIM 1280
#define NH    16
#define HD    80
#define HDP   96      // head dim padded to 3x32 for K=32 MFMA steps
#define SEG   512
#define RLS   80      // rope-epilogue LDS row stride

typedef __bf16 bf16;
typedef bf16  bf16x4 __attribute__((ext_vector_type(4)));
typedef bf16  bf16x8 __attribute__((ext_vector_type(8)));
typedef float f32x4  __attribute__((ext_vector_type(4)));

#define WAITVM(n) asm volatile("s_waitcnt vmcnt(" #n ")" ::: "memory")
#define SBAR()    asm volatile("s_barrier" ::: "memory")

__device__ __forceinline__ void gload16(const bf16* g, bf16* l) {
  __builtin_amdgcn_global_load_lds(
      (const __attribute__((address_space(1))) void*)g,
      (__attribute__((address_space(3))) void*)l, 16, 0, 0);
}

// ---------------------------------------------------------------------------
// Fused fp32->bf16 convert of hidden (1310720 f4), qkv_w (1228800 f4),
// proj_w (409600 f4). Grid covers 2949120 float4 groups.
// ---------------------------------------------------------------------------
__global__ __launch_bounds__(256) void cvt_all(
    const float* __restrict__ hid, const float* __restrict__ qw,
    const float* __restrict__ pw, bf16* __restrict__ hb,
    bf16* __restrict__ qwb, bf16* __restrict__ pwb)
{
  int i = blockIdx.x * 256 + threadIdx.x;
  const float* src; bf16* dst; int off;
  if (i < 1310720)      { src = hid; dst = hb;  off = i; }
  else if (i < 2539520) { src = qw;  dst = qwb; off = i - 1310720; }
  else                  { src = pw;  dst = pwb; off = i - 2539520; }
  float4 v = ((const float4*)src)[off];
  ((bf16x4*)dst)[off] = (bf16x4){(bf16)v.x, (bf16)v.y, (bf16)v.z, (bf16)v.w};
}

// ---------------------------------------------------------------------------
// K1: qkv GEMM, BM=128 BN=160 BK=64, 4 waves (2x2), wave = 64x80 (one head
// per wave-half), NK=20, 40 MFMA/wave/iter. 2-phase dbuf via
// global_load_lds; __syncthreads drains (proven K4-R10 structure).
// LDS rows 64 bf16 = 128 B = 8 chunks of 16 B: chunk c of row r holds
// logical chunk c ^ (r&7) (staging source pre-swizzle (tid&7)^((tid>>3)&7),
// frag-read deswizzle ((kk*4+quad)^(l15&7))*8; 128 B row stride = one bank
// revolution -> wave access at the 8-per-bank floor).
// Staging uniform 9 loads/thread (A rows er+32i i<4; B rows er+32i i<5).
// Grid: mt=lin/24, nt=lin%24 (24%8==0 => XCD=nt%8, W-tile L2-resident).
// Epilogue: Q/K -> wave LDS -> rope -> [h][t][96] chunks XOR-swizzled by
// ((t>>1)&3); V -> Vt[h][d][T] bf16x4 scatter.   (unchanged)
// ---------------------------------------------------------------------------
__global__ __launch_bounds__(256, 2) void gemm_qkv(
    const bf16* __restrict__ A, const bf16* __restrict__ W,
    const float* __restrict__ bias, const float* __restrict__ rot,
    bf16* __restrict__ Qh, bf16* __restrict__ Kh, bf16* __restrict__ Vt)
{
  constexpr int BM = 128, BN = 160, MI = 4, NJ = 5, BK = 64;
  constexpr int K = 1280;
  constexpr int ASLOT = BM * BK;                  // 8192 elems / slot
  constexpr int BSLOT = BN * BK;                  // 10240 elems / slot
  constexpr int STAGE = 2 * (ASLOT + BSLOT);      // 36864 elems = 73728 B
  constexpr int EPIB  = 4 * 64 * RLS;             // 20480 elems
  constexpr int LDSZ  = (STAGE > EPIB ? STAGE : EPIB);
  __shared__ __align__(16) bf16 smem[LDSZ];
  bf16* As = smem;                                // 2 slots
  bf16* Bs = smem + 2 * ASLOT;                    // 2 slots

  int tid  = threadIdx.x;
  int wave = tid >> 6, lane = tid & 63;
  int l15 = lane & 15, quad = lane >> 4;
  int l7  = l15 & 7;
  int mt = blockIdx.x / 24;
  int nt = blockIdx.x % 24;
  int m0 = mt * BM, n0 = nt * BN;
  int wm = (wave >> 1) * (BM / 2), wn = (wave & 1) * (BN / 2);

  int er  = tid >> 3;                             // staging row 0..31
  int ec8 = (((tid & 7) ^ ((tid >> 3) & 7)) * 8); // source chunk pre-swizzle
  const bf16* ga = A + (size_t)(m0 + er) * K + ec8;
  const bf16* gb = W + (size_t)(n0 + er) * K + ec8;

  auto issueN = [&](int k, int p) {               // uniform 9 VMEM/thread
    bf16* la = As + p * ASLOT + tid * 8;
    bf16* lb = Bs + p * BSLOT + tid * 8;
#pragma unroll
    for (int i = 0; i < 4; ++i)                   // A rows 0..127
      gload16(ga + (size_t)(32 * i) * K + k, la + i * 2048);
#pragma unroll
    for (int i = 0; i < 5; ++i)                   // B rows 0..159
      gload16(gb + (size_t)(32 * i) * K + k, lb + i * 2048);
  };

  f32x4 acc[MI][NJ];
#pragma unroll
  for (int i = 0; i < MI; ++i)
#pragma unroll
    for (int j = 0; j < NJ; ++j) acc[i][j] = (f32x4){0.f, 0.f, 0.f, 0.f};

  constexpr int NK = K / BK;                      // 20
  issueN(0, 0);
  for (int kt = 0; kt < NK; ++kt) {
    int p = kt & 1;
    __syncthreads();                      // drains DMA(kt) + prev frag reads
    if (kt + 1 < NK) issueN((kt + 1) * BK, p ^ 1);
    bf16x8 af[2][MI], bfr[2][NJ];
#pragma unroll
    for (int kk = 0; kk < 2; ++kk) {
      int co = ((kk * 4 + quad) ^ l7) * 8;        // deswizzled chunk
#pragma unroll
      for (int i = 0; i < MI; ++i)
        af[kk][i] = *(const bf16x8*)(As + p * ASLOT + (wm + i * 16 + l15) * 64 + co);
#pragma unroll
      for (int j = 0; j < NJ; ++j)
        bfr[kk][j] = *(const bf16x8*)(Bs + p * BSLOT + (wn + j * 16 + l15) * 64 + co);
    }
#pragma unroll
    for (int kk = 0; kk < 2; ++kk)
#pragma unroll
      for (int i = 0; i < MI; ++i)
#pragma unroll
        for (int j = 0; j < NJ; ++j)
          acc[i][j] = __builtin_amdgcn_mfma_f32_16x16x32_bf16(af[kk][i], bfr[kk][j], acc[i][j], 0, 0, 0);
  }

  int c0  = n0 + wn;                 // wave's first col = head base
  int sel = c0 / D_DIM;              // 0=Q, 1=K, 2=V (block-uniform)
  if (sel < 2) {
    // ---- fused rope epilogue ----
    __syncthreads();                 // all frag reads done; reuse smem
    bf16* Lw = smem + wave * (64 * RLS);
    int cc0 = c0 - sel * D_DIM;
    int h   = cc0 / HD;
#pragma unroll
    for (int j = 0; j < NJ; ++j) {
      float bv = bias[c0 + j * 16 + l15];
#pragma unroll
      for (int i = 0; i < MI; ++i)
#pragma unroll
        for (int r = 0; r < 4; ++r)
          Lw[(i * 16 + quad * 4 + r) * RLS + j * 16 + l15] = (bf16)(acc[i][j][r] + bv);
    }
    __syncthreads();
    int t = m0 + wm + lane;          // lane = local row
    bf16x4 x[20];
#pragma unroll
    for (int a = 0; a < 20; ++a)
      x[a] = *(const bf16x4*)(Lw + lane * RLS + a * 4);
    const float* fp = rot + t * 40;
    float fr[40];
#pragma unroll
    for (int a = 0; a < 10; ++a) {
      float4 f4 = *(const float4*)(fp + a * 4);
      fr[a * 4] = f4.x; fr[a * 4 + 1] = f4.y; fr[a * 4 + 2] = f4.z; fr[a * 4 + 3] = f4.w;
    }
    const float sc = (sel == 0) ? 0.11180339887498949f : 1.0f;
    bf16* dst = ((sel == 0) ? Qh : Kh) + ((size_t)h * T_DIM + t) * HDP;
    int ksw = (t >> 1) & 3;          // row chunk swizzle
#pragma unroll
    for (int g = 0; g < 5; ++g) {
      bf16x8 c1, c2;
#pragma unroll
      for (int bb = 0; bb < 8; ++bb) {
        int a = g * 2 + (bb >> 2), b = bb & 3;
        float cs, sn;
        __sincosf(fr[a * 4 + b], &sn, &cs);
        cs *= sc; sn *= sc;
        float xa = (float)x[a][b], xb = (float)x[a + 10][b];
        c1[bb] = (bf16)(xa * cs - xb * sn);
        c2[bb] = (bf16)(xb * cs + xa * sn);
      }
      *(bf16x8*)(dst + (g ^ ksw) * 8)       = c1;
      *(bf16x8*)(dst + ((g + 5) ^ ksw) * 8) = c2;
    }
    bf16x8 z = {};
    *(bf16x8*)(dst + (10 ^ ksw) * 8) = z;
    *(bf16x8*)(dst + (11 ^ ksw) * 8) = z;
  } else {
    // ---- V scatter (transposed, t-major) ----
#pragma unroll
    for (int j = 0; j < NJ; ++j) {
      int c = c0 + j * 16 + l15;
      float bv = bias[c];
      int cc = c - 2 * D_DIM;
      int h = cc / HD, d = cc - h * HD;
      bf16* vrow = Vt + ((size_t)h * HD + d) * T_DIM;
#pragma unroll
      for (int i = 0; i < MI; ++i) {
        int t0 = m0 + wm + i * 16 + quad * 4;
        bf16x4 pv = {(bf16)(acc[i][j][0] + bv), (bf16)(acc[i][j][1] + bv),
                     (bf16)(acc[i][j][2] + bv), (bf16)(acc[i][j][3] + bv)};
        *(bf16x4*)(vrow + t0) = pv;
      }
    }
  }
}

// ---------------------------------------------------------------------------
// K3: attention. Grid 1024; all 8 tiles of (seg,head) group g land on XCD
// g%8 => K/V L2-resident. K/V staged via global_load_lds into double
// buffers; one barrier per QK chunk; V(0) prefetch issued during the last
// QK chunk and drains behind the softmax VALU stretch. V chunks
// XOR-swizzled (chunk ^ (d&7)). Qh/Kh rows arrive chunk-swizzled by
// ((t>>1)&3) (from K1); qf/kb deswizzle. s_setprio(1) around MFMA clusters.
// P double-buffered per wave (2 x [16][128] bf16, XOR chunk swizzle
// (key>>3)^(row&7)); pwrite(kc+1) hoisted to overlap the V DMA drain.
// LDS 81920 B = exactly 2 blocks/CU.   (R9 form, unchanged)
// ---------------------------------------------------------------------------
__global__ __launch_bounds__(256, 2) void attn_kernel(
    const bf16* __restrict__ Qh, const bf16* __restrict__ Kh,
    const bf16* __restrict__ Vt, bf16* __restrict__ out)
{
  // KV double buffers 2 x 24576 B (K [128][96] / V [80][128]);
  // P 4 waves x 2 slabs x [16][128] bf16 = 32768 B  => 81920 B total
  __shared__ __align__(16) char smem[81920];
  bf16* KV[2] = {(bf16*)smem, (bf16*)(smem + 24576)};
  bf16* Pl    = (bf16*)(smem + 49152);

  int lin  = blockIdx.x;
  int g    = lin & 127;        // (seg,head) group
  int tile = lin >> 7;         // 0..7
  int h    = g & 15;
  int seg  = g >> 4;
  int seg0 = seg * SEG;
  int t0   = seg0 + tile * 64;

  int tid  = threadIdx.x;
  int wave = tid >> 6;
  int lane = tid & 63;
  int l15 = lane & 15, quad = lane >> 4;
  int qs8 = ((quad ^ ((l15 >> 1) & 3)) * 8);   // Qh/Kh chunk deswizzle
  int tw = t0 + wave * 16;

  const bf16* khbase = Kh + ((size_t)h * T_DIM + seg0) * HDP;
  const bf16* vtbase = Vt + (size_t)h * HD * T_DIM + seg0;

  auto issueK = [&](int kc, bf16* buf) {
    const bf16* src = khbase + (size_t)kc * (128 * HDP);
#pragma unroll
    for (int i = 0; i < 6; ++i)
      gload16(src + (i * 256 + tid) * 8, buf + (i * 256 + tid) * 8);
  };
  auto issueV = [&](int kc, bf16* buf) {
    const bf16* src = vtbase + kc * 128;
#pragma unroll
    for (int i = 0; i < 5; ++i) {
      int idx = i * 256 + tid;            // 0..1279
      int d = idx >> 4, ch = idx & 15;
      int chg = ch ^ (d & 7);             // XOR source-chunk swizzle
      gload16(src + (size_t)d * T_DIM + chg * 8, buf + idx * 8);
    }
  };

  issueK(0, KV[0]);

  bf16x8 qf[3];
  {
    const bf16* qbase = Qh + ((size_t)h * T_DIM + tw + l15) * HDP + qs8;
#pragma unroll
    for (int kk = 0; kk < 3; ++kk) qf[kk] = *(const bf16x8*)(qbase + kk * 32);
  }

  // ---- Phase A: S = Q K^T, 4 chunks of 128 keys, 1 barrier/chunk ----
  f32x4 S[4][8];
  for (int kc = 0; kc < 4; ++kc) {
    bf16* buf = KV[kc & 1];
    __syncthreads();                       // drains DMA(kc) + prior reads
    if (kc < 3) issueK(kc + 1, KV[(kc & 1) ^ 1]);
    else        issueV(0, KV[0]);          // KV[0] free (last read chunk 2)
    __builtin_amdgcn_s_setprio(1);
#pragma unroll
    for (int j = 0; j < 8; ++j) {
      f32x4 acc = {0.f, 0.f, 0.f, 0.f};
      const bf16* kb = buf + (j * 16 + l15) * HDP + qs8;
#pragma unroll
      for (int kk = 0; kk < 3; ++kk)
        acc = __builtin_amdgcn_mfma_f32_16x16x32_bf16(qf[kk], *(const bf16x8*)(kb + kk * 32), acc, 0, 0, 0);
      S[kc][j] = acc;
    }
    __builtin_amdgcn_s_setprio(0);
  }

  // ---- Softmax (exact; scale pre-folded into Q). V(0) in flight. ----
  float vsum[4];
#pragma unroll
  for (int r = 0; r < 4; ++r) {
    float m = -1e30f;
#pragma unroll
    for (int kc = 0; kc < 4; ++kc)
#pragma unroll
      for (int j = 0; j < 8; ++j) m = fmaxf(m, S[kc][j][r]);
    for (int off = 1; off < 16; off <<= 1) m = fmaxf(m, __shfl_xor(m, off));
    float s = 0.f;
#pragma unroll
    for (int kc = 0; kc < 4; ++kc)
#pragma unroll
      for (int j = 0; j < 8; ++j) {
        float e = __expf(S[kc][j][r] - m);
        S[kc][j][r] = e;
        s += e;
      }
    for (int off = 1; off < 16; off <<= 1) s += __shfl_xor(s, off);
    vsum[r] = s;
  }

  // ---- Phase B: O = P V, 4 chunks, V prefetched one chunk ahead,
  //      P-writes double-buffered and hoisted to overlap the V DMA ----
  f32x4 O[5];
#pragma unroll
  for (int n = 0; n < 5; ++n) O[n] = (f32x4){0.f, 0.f, 0.f, 0.f};
  bf16* P0 = Pl + wave * 4096;             // two 2048-elem slabs per wave

  // P store layout: slab[row*128 + (((key>>3)^(row&7))<<3 | (key&7))]
  auto pwrite = [&](int kc, bf16* slab) {
#pragma unroll
    for (int j = 0; j < 8; ++j)
#pragma unroll
      for (int r = 0; r < 4; ++r) {
        int row = quad * 4 + r;
        int key = j * 16 + l15;
        slab[row * 128 + ((((key >> 3) ^ (row & 7)) << 3) | (key & 7))] =
            (bf16)S[kc][j][r];
      }
  };

  pwrite(0, P0);                           // overlaps V(0) DMA drain
  for (int kc = 0; kc < 4; ++kc) {
    bf16* vbuf = KV[kc & 1];
    bf16* slab = P0 + (kc & 1) * 2048;
    __syncthreads();                       // drains V(kc); prior V reads done
    if (kc < 3) {
      issueV(kc + 1, KV[(kc & 1) ^ 1]);
      pwrite(kc + 1, P0 + ((kc + 1) & 1) * 2048);   // overlaps V(kc+1) DMA
    }
    __builtin_amdgcn_s_setprio(1);
#pragma unroll
    for (int ks = 0; ks < 4; ++ks) {
      // row = l15, keys ks*32 + quad*8 + [0..8): one 16B chunk, deswizzled
      bf16x8 pa = *(const bf16x8*)(slab + l15 * 128 +
                                   (((ks * 4 + quad) ^ (l15 & 7)) << 3));
#pragma unroll
      for (int n = 0; n < 5; ++n) {
        int d = n * 16 + l15;
        // global chunk (ks*4+quad) lives at LDS chunk ^(d&7)
        int chl = (ks * 4 + quad) ^ (d & 7);
        bf16x8 vb = *(const bf16x8*)(vbuf + d * 128 + chl * 8);
        O[n] = __builtin_amdgcn_mfma_f32_16x16x32_bf16(pa, vb, O[n], 0, 0, 0);
      }
    }
    __builtin_amdgcn_s_setprio(0);
  }

#pragma unroll
  for (int n = 0; n < 5; ++n)
#pragma unroll
    for (int r = 0; r < 4; ++r) {
      int row = tw + quad * 4 + r;
      int col = h * HD + n * 16 + l15;
      out[(size_t)row * D_DIM + col] = (bf16)(O[n][r] / vsum[r]);
    }
}

// ---------------------------------------------------------------------------
// K4: proj GEMM, BM=64 BN=160 BK=64, 4 waves, wave = 32x80 (MI=2, NJ=5,
// kk=2 => 20 MFMA/wave/iter, NK=20). Grid 64x8 = 512 blocks = exactly 2/CU.
// 2-slot dbuf via global_load_lds, __syncthreads drain per iter. LDS
// 65536 B => 2 blocks/CU. Rows = 128 B = 8 chunks, 3-bit XOR swizzle.
// B staged as 192 rows (uniform 8 VMEM/thread; pad rows 160..191 source-
// clamped, never read). fp32 out + bias. A-sharing: lin%8 == mt%8.
// (R10 form, VALIDATED; unchanged)
// ---------------------------------------------------------------------------
__global__ __launch_bounds__(256, 2) void gemm_proj(
    const bf16* __restrict__ A, const bf16* __restrict__ W,
    const float* __restrict__ bias, float* __restrict__ out)
{
  constexpr int BM = 64, BN = 160, MI = 2, NJ = 5;
  constexpr int K = 1280, N = 1280, BK = 64;
  constexpr int ASLOT = BM * BK;            // 4096 elems (8 KB)
  constexpr int BSLOT = 192 * BK;           // 12288 elems (24 KB)
  __shared__ __align__(16) bf16 smem[2 * (ASLOT + BSLOT)];   // 65536 B
  bf16* As = smem;                          // 2 slots
  bf16* Bs = smem + 2 * ASLOT;              // 2 slots

  int tid  = threadIdx.x;
  int wave = tid >> 6, lane = tid & 63;
  int l15 = lane & 15, quad = lane >> 4;
  int l7  = l15 & 7;
  int tiles_m = 64;                         // 4096/64
  int mt = blockIdx.x % tiles_m;            // lin%8 == mt%8 -> A-tile per XCD
  int nt = blockIdx.x / tiles_m;            // 0..7
  int m0 = mt * BM, n0 = nt * BN;
  int wm = (wave >> 1) * (BM / 2), wn = (wave & 1) * (BN / 2);

  int er  = tid >> 3;                       // staging row 0..31
  int ec8 = (((tid & 7) ^ ((tid >> 3) & 7)) * 8);  // source chunk pre-swizzle
  const bf16* ga = A + (size_t)(m0 + er) * K + ec8;
  const bf16* gb = W + (size_t)(n0 + er) * K + ec8;

  auto issueN = [&](int k, int s) {        // uniform 8 VMEM instrs/thread
    bf16* la = As + s * ASLOT + tid * 8;
    bf16* lb = Bs + s * BSLOT + tid * 8;
    gload16(ga + k, la);                             // A rows 0..31
    gload16(ga + (size_t)32 * K + k, la + 2048);     // A rows 32..63
#pragma unroll
    for (int i = 0; i < 5; ++i)                      // B rows 0..159
      gload16(gb + (size_t)(32 * i) * K + k, lb + i * 2048);
    // B rows 160..191 are pad: clamp source to rows 96..127 (never read)
    gload16(gb + (size_t)96 * K + k, lb + 5 * 2048);
  };

  f32x4 acc[MI][NJ];
#pragma unroll
  for (int i = 0; i < MI; ++i)
#pragma unroll
    for (int j = 0; j < NJ; ++j) acc[i][j] = (f32x4){0.f, 0.f, 0.f, 0.f};

  constexpr int NK = K / BK;               // 20
  issueN(0, 0);
  for (int kt = 0; kt < NK; ++kt) {
    int p = kt & 1;
    __syncthreads();                       // drains DMA(kt) + prior frag reads
    if (kt + 1 < NK) issueN((kt + 1) * BK, p ^ 1);
    bf16x8 af[2][MI], bfr[2][NJ];
#pragma unroll
    for (int kk = 0; kk < 2; ++kk) {
      int co = ((kk * 4 + quad) ^ l7) * 8;           // deswizzled chunk
#pragma unroll
      for (int i = 0; i < MI; ++i)
        af[kk][i] = *(const bf16x8*)(As + p * ASLOT + (wm + i * 16 + l15) * 64 + co);
#pragma unroll
      for (int j = 0; j < NJ; ++j)
        bfr[kk][j] = *(const bf16x8*)(Bs + p * BSLOT + (wn + j * 16 + l15) * 64 + co);
    }
    __builtin_amdgcn_s_setprio(1);
#pragma unroll
    for (int kk = 0; kk < 2; ++kk)
#pragma unroll
      for (int i = 0; i < MI; ++i)
#pragma unroll
        for (int j = 0; j < NJ; ++j)
          acc[i][j] = __builtin_amdgcn_mfma_f32_16x16x32_bf16(af[kk][i], bfr[kk][j], acc[i][j], 0, 0, 0);
    __builtin_amdgcn_s_setprio(0);
  }

#pragma unroll
  for (int j = 0; j < NJ; ++j) {
    int col = n0 + wn + j * 16 + l15;
    float bv = bias[col];
#pragma unroll
    for (int i = 0; i < MI; ++i)
#pragma unroll
      for (int r = 0; r < 4; ++r) {
        int row = m0 + wm + i * 16 + quad * 4 + r;
        out[(size_t)row * N + col] = acc[i][j][r] + bv;
      }
  }
}

// ---------------------------------------------------------------------------
extern "C" void kernel_launch(void* const* d_in, const int* in_sizes, int n_in,
                              void* d_out, int out_size, void* d_ws, size_t ws_size,
                              hipStream_t stream)
{
  const float* hidden = (const float*)d_in[0];
  // d_in[1]: cu_seqlens (int32) — fixed 8x512 segments, handled structurally
  const float* rot    = (const float*)d_in[2];
  const float* qkv_w  = (const float*)d_in[3];
  const float* qkv_b  = (const float*)d_in[4];
  const float* proj_w = (const float*)d_in[5];
  const float* proj_b = (const float*)d_in[6];
  float* out = (float*)d_out;

  char* ws = (char*)d_ws;
  bf16* qkvw_bf  = (bf16*)(ws);              //  9,830,400 B [3840][1280]
  bf16* projw_bf = (bf16*)(ws +  9830400);   //  3,276,800 B [1280][1280]
  bf16* hid_bf   = (bf16*)(ws + 13107200);   // 10,485,760 B [4096][1280]
  bf16* attn     = (bf16*)(ws + 13107200);   // reuses hid_bf (dead after K1)
  bf16* Qh       = (bf16*)(ws + 23592960);   // 12,582,912 B [16][4096][96]
  bf16* Kh       = (bf16*)(ws + 36175872);   // 12,582,912 B
  bf16* Vt       = (bf16*)(ws + 48758784);   // 10,485,760 B [16][80][4096]
                                             // total 59,244,544 B

  cvt_all<<<dim3(11520), dim3(256), 0, stream>>>(
      hidden, qkv_w, proj_w, hid_bf, qkvw_bf, projw_bf);
  // K1: qkv GEMM + fused rope, 32x24 tiles of 128x160 BK=64, XCD = nt%8
  gemm_qkv<<<dim3(768), dim3(256), 0, stream>>>(
      hid_bf, qkvw_bf, qkv_b, rot, Qh, Kh, Vt);
  // K3: block-diagonal attention, group->XCD co-located grid
  attn_kernel<<<dim3(1024), dim3(256), 0, stream>>>(Qh, Kh, Vt, attn);
  // K4: proj GEMM, 64x8 tiles of 64x160 BK=64, dbuf, 2/CU exact
  gemm_proj<<<dim3(512), dim3(256), 0, stream>>>(
      attn, projw_bf, proj_b, out);
}